// Round 3
// baseline (6853.970 us; speedup 1.0000x reference)
//
#include <hip/hip_runtime.h>
#include <hip/hip_bf16.h>
#include <math.h>

typedef __hip_bfloat16 bf16;

// ---------------- constants ----------------
#define BSZ   8
#define TLEN  8192
#define NFEAT 256
#define DM    512
#define NHEAD_ 8
#define HD    64
#define SP    256          // NPATCH
#define KL    32
#define FFD   2048
#define DI    1024
#define DST   16
#define NPHD  41
#define MROWS (BSZ*SP)     // 2048

__device__ __forceinline__ float b2f(bf16 v) { return __bfloat162float(v); }

__device__ __forceinline__ float ldA(const float* p, size_t i) { return p[i]; }
__device__ __forceinline__ float ldA(const bf16* p, size_t i)  { return b2f(p[i]); }
__device__ __forceinline__ void stO(float* p, size_t i, float v) { p[i] = v; }
__device__ __forceinline__ void stO(bf16* p, size_t i, float v)  { p[i] = __float2bfloat16(v); }

// ---------------- block reduce (sum of two values) over 256 threads ----------------
__device__ __forceinline__ void blk_red_sum2(float& s1, float& s2) {
    __shared__ float buf1[4], buf2[4];
    #pragma unroll
    for (int off = 32; off > 0; off >>= 1) {
        s1 += __shfl_down(s1, off, 64);
        s2 += __shfl_down(s2, off, 64);
    }
    int lane = threadIdx.x & 63, w = threadIdx.x >> 6;
    __syncthreads();
    if (lane == 0) { buf1[w] = s1; buf2[w] = s2; }
    __syncthreads();
    s1 = buf1[0] + buf1[1] + buf1[2] + buf1[3];
    s2 = buf2[0] + buf2[1] + buf2[2] + buf2[3];
}

// ---------------- stage A: day-scale + gauss conv + patch LN(8192) ----------------
__global__ void patch_kernel(const float* __restrict__ x, const float* __restrict__ dw,
                             const float* __restrict__ db, const float* __restrict__ gk,
                             const float* __restrict__ g1, const float* __restrict__ b1,
                             const int* __restrict__ day_idx, bf16* __restrict__ pe_v)
{
    __shared__ float xs[51][256];    // 51 KB
    int blk = blockIdx.x;
    int b = blk >> 8, p = blk & 255;
    int f = threadIdx.x;
    int di = day_idx[b];
    float w  = dw[di * NFEAT + f];
    float bb = db[di * NFEAT + f];
    int t0 = p * KL - 10;
    for (int r = 0; r < 51; ++r) {
        int t = t0 + r;
        xs[r][f] = (t >= 0 && t < TLEN) ? x[((size_t)b * TLEN + t) * NFEAT + f] * w + bb : 0.f;
    }
    float gkr[20];
    #pragma unroll
    for (int k = 0; k < 20; ++k) gkr[k] = gk[f * 20 + k];
    __syncthreads();

    float c[32];
    float sum = 0.f, sumsq = 0.f;
    #pragma unroll
    for (int i = 0; i < 32; ++i) {
        float acc = 0.f;
        #pragma unroll
        for (int k = 0; k < 20; ++k) acc += xs[i + k][f] * gkr[k];
        c[i] = acc; sum += acc; sumsq += acc * acc;
    }
    blk_red_sum2(sum, sumsq);
    float mean = sum * (1.f / 8192.f);
    float var  = sumsq * (1.f / 8192.f) - mean * mean;
    float rstd = rsqrtf(fmaxf(var, 0.f) + 1e-6f);
    bf16* outp = pe_v + (size_t)blk * 8192;
    #pragma unroll
    for (int i = 0; i < 32; ++i) {
        int e = i * 256 + f;
        outp[e] = __float2bfloat16((c[i] - mean) * rstd * g1[e] + b1[e]);
    }
}

// ---------------- generic GEMM: out = act(A[MxK] @ B[f32 KxN] + bias) (+residual) ----
// act: 0 none, 1 gelu(exact), 2 softplus.
#define BM 64
#define BN 64
#define BKK 16
template<typename TA>
__global__ void gemm_kernel(const TA* __restrict__ A, const float* __restrict__ Bw,
                            const float* __restrict__ bias, const float* __restrict__ residual,
                            float* __restrict__ outF, bf16* __restrict__ outB,
                            int M, int N, int K, int act)
{
    __shared__ float As[BKK][BM + 4];
    __shared__ float Bs[BKK][BN + 4];
    int n0 = blockIdx.x * BN, m0 = blockIdx.y * BM;
    int tid = threadIdx.x;
    int tx = tid & 15, ty = tid >> 4;
    float acc[4][4] = {};
    for (int k0 = 0; k0 < K; k0 += BKK) {
        for (int i = tid; i < BM * BKK; i += 256) {
            int m = i >> 4, k = i & 15;
            As[k][m] = ldA(A, (size_t)(m0 + m) * K + k0 + k);
        }
        for (int i = tid; i < BKK * BN; i += 256) {
            int k = i >> 6, n = i & 63;
            int gn = n0 + n;
            Bs[k][n] = (gn < N) ? Bw[(size_t)(k0 + k) * N + gn] : 0.f;
        }
        __syncthreads();
        #pragma unroll
        for (int k = 0; k < BKK; ++k) {
            float a[4], bb[4];
            #pragma unroll
            for (int i = 0; i < 4; ++i) a[i] = As[k][ty * 4 + i];
            #pragma unroll
            for (int j = 0; j < 4; ++j) bb[j] = Bs[k][tx * 4 + j];
            #pragma unroll
            for (int i = 0; i < 4; ++i)
                #pragma unroll
                for (int j = 0; j < 4; ++j) acc[i][j] += a[i] * bb[j];
        }
        __syncthreads();
    }
    #pragma unroll
    for (int i = 0; i < 4; ++i) {
        int m = m0 + ty * 4 + i;
        #pragma unroll
        for (int j = 0; j < 4; ++j) {
            int n = n0 + tx * 4 + j;
            if (n >= N) continue;
            float v = acc[i][j];
            v += bias[n];
            if (act == 1)      v = 0.5f * v * (1.f + erff(v * 0.7071067811865476f));
            else if (act == 2) v = (v > 20.f) ? v : log1pf(__expf(v));
            if (residual) v += residual[(size_t)m * N + n];
            if (outB) stO(outB, (size_t)m * N + n, v);
            else      stO(outF, (size_t)m * N + n, v);
        }
    }
}

// ---------------- LayerNorm over dim 512 ----------------
__global__ void ln_kernel(const float* __restrict__ in, const float* __restrict__ g,
                          const float* __restrict__ bta, float* __restrict__ out, float eps)
{
    int row = blockIdx.x, tid = threadIdx.x;
    const float* r = in + (size_t)row * DM;
    float v0 = r[tid], v1 = r[tid + 256];
    float s1 = v0 + v1, s2 = v0 * v0 + v1 * v1;
    blk_red_sum2(s1, s2);
    float mean = s1 * (1.f / 512.f);
    float var  = s2 * (1.f / 512.f) - mean * mean;
    float rstd = rsqrtf(fmaxf(var, 0.f) + eps);
    float* o = out + (size_t)row * DM;
    o[tid]       = (v0 - mean) * rstd * g[tid]       + bta[tid];
    o[tid + 256] = (v1 - mean) * rstd * g[tid + 256] + bta[tid + 256];
}

// ---------------- attention: one block per (b,h,q) ----------------
__global__ void attn_kernel(const float* __restrict__ qkv, const float* __restrict__ rel_table,
                            float* __restrict__ attno)
{
    __shared__ float qv[64];
    __shared__ float sc[256];
    __shared__ float rb[256];
    __shared__ float op[4][64];
    int blk = blockIdx.x;
    int q = blk & 255, bh = blk >> 8;
    int hh = bh & 7, b = bh >> 3;
    int tid = threadIdx.x;
    const float* base = qkv + (size_t)b * 256 * 1536;
    if (tid < 64) qv[tid] = base[(size_t)q * 1536 + hh * 64 + tid];
    __syncthreads();
    const float* krow = base + (size_t)tid * 1536 + 512 + hh * 64;
    float d = 0.f;
    #pragma unroll 16
    for (int i = 0; i < 64; ++i) d += qv[i] * krow[i];
    float s = d * 0.125f;
    int rel = tid - q; rel = rel < -128 ? -128 : (rel > 128 ? 128 : rel);
    s += rel_table[hh * 257 + rel + 128];
    if (tid > q) s += -1e9f;
    sc[tid] = s; rb[tid] = s;
    __syncthreads();
    for (int st = 128; st > 0; st >>= 1) { if (tid < st) rb[tid] = fmaxf(rb[tid], rb[tid + st]); __syncthreads(); }
    float mx = rb[0];
    __syncthreads();
    float e = __expf(s - mx);
    sc[tid] = e; rb[tid] = e;
    __syncthreads();
    for (int st = 128; st > 0; st >>= 1) { if (tid < st) rb[tid] += rb[tid + st]; __syncthreads(); }
    float inv = 1.f / rb[0];
    __syncthreads();
    int dd = tid & 63, c = tid >> 6;
    const float* vbase = base + 1024 + hh * 64 + dd;
    float o = 0.f;
    for (int k = c * 64; k < c * 64 + 64; ++k) o += sc[k] * vbase[(size_t)k * 1536];
    op[c][dd] = o;
    __syncthreads();
    if (tid < 64) {
        float r = (op[0][tid] + op[1][tid] + op[2][tid] + op[3][tid]) * inv;
        attno[((size_t)(b * 256 + q)) * DM + hh * 64 + tid] = r;
    }
}

// ---------------- mamba depthwise conv (k=4 causal) + silu ----------------
__global__ void mamba_conv_kernel(const bf16* __restrict__ xz, const float* __restrict__ cW,
                                  const float* __restrict__ cb, bf16* __restrict__ xc)
{
    int row = blockIdx.x;
    int b = row >> 8, t = row & 255;
    int tid = threadIdx.x;
    #pragma unroll
    for (int j = 0; j < 4; ++j) {
        int dd = tid + j * 256;
        float acc = cb[dd];
        #pragma unroll
        for (int k = 0; k < 4; ++k) {
            int ts = t - 3 + k;
            if (ts >= 0) acc += b2f(xz[((size_t)(b * 256 + ts)) * 2048 + dd]) * cW[dd * 4 + k];
        }
        xc[(size_t)row * DI + dd] = __float2bfloat16(acc * (1.f / (1.f + __expf(-acc))));
    }
}

// ---------------- selective scan: block = 16 d x 16 s, grid = B * (DI/16) ----------------
__global__ void scan_kernel(const float* __restrict__ delta, const bf16* __restrict__ xcv,
                            const float* __restrict__ bc, const bf16* __restrict__ xz,
                            const float* __restrict__ Alog, const float* __restrict__ Dp,
                            float* __restrict__ y)
{
    int blk = blockIdx.x;
    int b = blk >> 6, chunk = blk & 63;
    int tid = threadIdx.x;
    int s = tid & 15, dl = tid >> 4;
    int d = chunk * 16 + dl;
    float A  = -__expf(Alog[d * DST + s]);
    float Dv = Dp[d];
    float h = 0.f;
    for (int t = 0; t < 256; ++t) {
        size_t r = (size_t)(b * 256 + t);
        float dt = delta[r * DI + d];
        float u  = b2f(xcv[r * DI + d]);
        float Bv = bc[r * 32 + s];
        float Cv = bc[r * 32 + 16 + s];
        h = __expf(dt * A) * h + dt * Bv * u;
        float contrib = h * Cv;
        contrib += __shfl_xor(contrib, 1, 64);
        contrib += __shfl_xor(contrib, 2, 64);
        contrib += __shfl_xor(contrib, 4, 64);
        contrib += __shfl_xor(contrib, 8, 64);
        if (s == 0) {
            float z = b2f(xz[r * 2048 + DI + d]);
            y[r * DI + d] = (contrib + u * Dv) * (z * (1.f / (1.f + __expf(-z))));
        }
    }
}

// ---------------- host side ----------------
template<typename TA>
static inline void launch_gemm(hipStream_t st, const TA* A, const float* Bw, const float* bias,
                               const float* res, float* outF, bf16* outB, int M, int N, int K, int act)
{
    dim3 grid((N + BN - 1) / BN, M / BM);
    gemm_kernel<TA><<<grid, 256, 0, st>>>(A, Bw, bias, res, outF, outB, M, N, K, act);
}

extern "C" void kernel_launch(void* const* d_in, const int* in_sizes, int n_in,
                              void* d_out, int out_size, void* d_ws, size_t ws_size,
                              hipStream_t stream)
{
    const float* x_in     = (const float*)d_in[0];
    const float* day_w    = (const float*)d_in[1];
    const float* day_b    = (const float*)d_in[2];
    const float* gauss    = (const float*)d_in[3];
    const float* pe_ln1_g = (const float*)d_in[4];
    const float* pe_ln1_b = (const float*)d_in[5];
    const float* pe_W     = (const float*)d_in[6];
    const float* pe_b     = (const float*)d_in[7];
    const float* pe_ln2_g = (const float*)d_in[8];
    const float* pe_ln2_b = (const float*)d_in[9];
    const float* rel_tab  = (const float*)d_in[10];
    const float* tf_ln_g  = (const float*)d_in[11];
    const float* tf_ln_b  = (const float*)d_in[12];
    const float* tf_qkv_W = (const float*)d_in[13];
    const float* tf_qkv_b = (const float*)d_in[14];
    const float* tf_out_W = (const float*)d_in[15];
    const float* tf_out_b = (const float*)d_in[16];
    const float* tf_ffln_g= (const float*)d_in[17];
    const float* tf_ffln_b= (const float*)d_in[18];
    const float* tf_fc1_W = (const float*)d_in[19];
    const float* tf_fc1_b = (const float*)d_in[20];
    const float* tf_fc2_W = (const float*)d_in[21];
    const float* tf_fc2_b = (const float*)d_in[22];
    const float* mb_norm_g= (const float*)d_in[23];
    const float* mb_norm_b= (const float*)d_in[24];
    const float* mb_in_W  = (const float*)d_in[25];
    const float* mb_in_b  = (const float*)d_in[26];
    const float* mb_conv_W= (const float*)d_in[27];
    const float* mb_conv_b= (const float*)d_in[28];
    const float* mb_xp_W  = (const float*)d_in[29];
    const float* mb_xp_b  = (const float*)d_in[30];
    const float* mb_dt_W  = (const float*)d_in[31];
    const float* mb_dt_b  = (const float*)d_in[32];
    const float* mb_Alog  = (const float*)d_in[33];
    const float* mb_D     = (const float*)d_in[34];
    const float* mb_out_W = (const float*)d_in[35];
    const float* mb_out_b = (const float*)d_in[36];
    const float* head_W   = (const float*)d_in[37];
    const float* head_b   = (const float*)d_in[38];
    const int*   day_idx  = (const int*)d_in[39];

    // ---- workspace layout (byte-based; peak usage 36.25 MB) ----
    char* base = (char*)d_ws;
    float* x_state = (float*)base;                       // 4 MB
    char* arena = base + ((size_t)4 << 20);

    // stage A
    bf16* pe_v = (bf16*)arena;                           // 32 MB
    // transformer stage
    float* hbuf  = (float*)arena;                        // 4 MB
    float* qkvb  = (float*)(arena + ((size_t)4  << 20)); // 12 MB
    float* attno = (float*)(arena + ((size_t)16 << 20)); // 4 MB
    bf16*  ffb   = (bf16*) (arena + ((size_t)20 << 20)); // 8 MB
    // mamba stage (hbuf reused at arena)
    bf16*  xzb   = (bf16*) (arena + ((size_t)4  << 20)); // 8 MB
    bf16*  xcb   = (bf16*) (arena + ((size_t)12 << 20)); // 4 MB
    float* deltab= (float*)(arena + ((size_t)16 << 20)); // 8 MB
    float* yb    = (float*)(arena + ((size_t)24 << 20)); // 8 MB
    float* bcb   = (float*)(arena + ((size_t)32 << 20)); // 0.25 MB

    // ---- stage A: patch embed ----
    patch_kernel<<<MROWS, 256, 0, stream>>>(x_in, day_w, day_b, gauss, pe_ln1_g, pe_ln1_b,
                                            day_idx, pe_v);
    launch_gemm(stream, pe_v, pe_W, pe_b, (const float*)nullptr, x_state, (bf16*)nullptr,
                MROWS, DM, KL * NFEAT, 0);
    ln_kernel<<<MROWS, 256, 0, stream>>>(x_state, pe_ln2_g, pe_ln2_b, x_state, 1e-6f);

    // ---- transformer blocks ----
    for (int i = 0; i < 2; ++i) {
        ln_kernel<<<MROWS, 256, 0, stream>>>(x_state, tf_ln_g + i * DM, tf_ln_b + i * DM, hbuf, 1e-5f);
        launch_gemm(stream, hbuf, tf_qkv_W + (size_t)i * DM * 3 * DM, tf_qkv_b + i * 3 * DM,
                    (const float*)nullptr, qkvb, (bf16*)nullptr, MROWS, 3 * DM, DM, 0);
        attn_kernel<<<BSZ * NHEAD_ * SP, 256, 0, stream>>>(qkvb, rel_tab, attno);
        launch_gemm(stream, attno, tf_out_W + (size_t)i * DM * DM, tf_out_b + i * DM,
                    x_state, x_state, (bf16*)nullptr, MROWS, DM, DM, 0);
        ln_kernel<<<MROWS, 256, 0, stream>>>(x_state, tf_ffln_g + i * DM, tf_ffln_b + i * DM, hbuf, 1e-5f);
        launch_gemm(stream, hbuf, tf_fc1_W + (size_t)i * DM * FFD, tf_fc1_b + i * FFD,
                    (const float*)nullptr, (float*)nullptr, ffb, MROWS, FFD, DM, 1);
        launch_gemm(stream, ffb, tf_fc2_W + (size_t)i * FFD * DM, tf_fc2_b + i * DM,
                    x_state, x_state, (bf16*)nullptr, MROWS, DM, FFD, 0);
    }

    // ---- mamba blocks ----
    for (int i = 0; i < 4; ++i) {
        ln_kernel<<<MROWS, 256, 0, stream>>>(x_state, mb_norm_g + i * DM, mb_norm_b + i * DM, hbuf, 1e-5f);
        launch_gemm(stream, hbuf, mb_in_W + (size_t)i * DM * 2 * DI, mb_in_b + i * 2 * DI,
                    (const float*)nullptr, (float*)nullptr, xzb, MROWS, 2 * DI, DM, 0);
        mamba_conv_kernel<<<MROWS, 256, 0, stream>>>(xzb, mb_conv_W + (size_t)i * DI * 4,
                                                     mb_conv_b + i * DI, xcb);
        launch_gemm(stream, xcb, mb_xp_W + (size_t)i * DI * 2 * DST, mb_xp_b + i * 2 * DST,
                    (const float*)nullptr, bcb, (bf16*)nullptr, MROWS, 2 * DST, DI, 0);
        launch_gemm(stream, xcb, mb_dt_W + (size_t)i * DI * DI, mb_dt_b + i * DI,
                    (const float*)nullptr, deltab, (bf16*)nullptr, MROWS, DI, DI, 2);
        scan_kernel<<<BSZ * (DI / 16), 256, 0, stream>>>(deltab, xcb, bcb, xzb,
                                                         mb_Alog + (size_t)i * DI * DST,
                                                         mb_D + i * DI, yb);
        launch_gemm(stream, yb, mb_out_W + (size_t)i * DI * DM, mb_out_b + i * DM,
                    x_state, x_state, (bf16*)nullptr, MROWS, DM, DI, 0);
    }

    // ---- head ----
    launch_gemm(stream, x_state, head_W, head_b, (const float*)nullptr, (float*)d_out, (bf16*)nullptr,
                MROWS, NPHD, DM, 0);
}

// Round 4
// 4003.753 us; speedup vs baseline: 1.7119x; 1.7119x over previous
//
#include <hip/hip_runtime.h>
#include <hip/hip_bf16.h>
#include <math.h>

typedef __hip_bfloat16 bf16;
typedef __attribute__((ext_vector_type(8))) short short8;
typedef __attribute__((ext_vector_type(4))) float floatx4;

// ---------------- constants ----------------
#define BSZ   8
#define TLEN  8192
#define NFEAT 256
#define DM    512
#define NHEAD_ 8
#define HD    64
#define SP    256          // NPATCH
#define KL    32
#define FFD   2048
#define DI    1024
#define DST   16
#define NPHD  41
#define MROWS (BSZ*SP)     // 2048

__device__ __forceinline__ float b2f(bf16 v) { return __bfloat162float(v); }
__device__ __forceinline__ short f2bs(float f) {
    union { bf16 h; short s; } u; u.h = __float2bfloat16(f); return u.s;
}

__device__ __forceinline__ float ldA(const float* p, size_t i) { return p[i]; }
__device__ __forceinline__ float ldA(const bf16* p, size_t i)  { return b2f(p[i]); }
__device__ __forceinline__ void stO(float* p, size_t i, float v) { p[i] = v; }
__device__ __forceinline__ void stO(bf16* p, size_t i, float v)  { p[i] = __float2bfloat16(v); }

// load 4 consecutive elems as bf16 bit-patterns
__device__ __forceinline__ short4 ld4bf(const float* p) {
    float4 v = *(const float4*)p;
    short4 r; r.x = f2bs(v.x); r.y = f2bs(v.y); r.z = f2bs(v.z); r.w = f2bs(v.w);
    return r;
}
__device__ __forceinline__ short4 ld4bf(const short* p) {
    return *(const short4*)p;
}

// ---------------- block reduce (sum of two values) over 256 threads ----------------
__device__ __forceinline__ void blk_red_sum2(float& s1, float& s2) {
    __shared__ float buf1[4], buf2[4];
    #pragma unroll
    for (int off = 32; off > 0; off >>= 1) {
        s1 += __shfl_down(s1, off, 64);
        s2 += __shfl_down(s2, off, 64);
    }
    int lane = threadIdx.x & 63, w = threadIdx.x >> 6;
    __syncthreads();
    if (lane == 0) { buf1[w] = s1; buf2[w] = s2; }
    __syncthreads();
    s1 = buf1[0] + buf1[1] + buf1[2] + buf1[3];
    s2 = buf2[0] + buf2[1] + buf2[2] + buf2[3];
}

// ---------------- weight transpose+convert: in fp32 [K][N] -> out bf16 [N][K] ----------------
__global__ void transpose_cvt(const float* __restrict__ in, short* __restrict__ out,
                              int K, int N, size_t in_ls, size_t out_ls)
{
    __shared__ float tile[32][33];
    const float* inp = in + (size_t)blockIdx.z * in_ls;
    short* outp = out + (size_t)blockIdx.z * out_ls;
    int kb = blockIdx.y * 32, nb = blockIdx.x * 32;
    int tx = threadIdx.x & 31, ty8 = threadIdx.x >> 5;
    #pragma unroll
    for (int r = 0; r < 32; r += 8)
        tile[ty8 + r][tx] = inp[(size_t)(kb + ty8 + r) * N + nb + tx];
    __syncthreads();
    #pragma unroll
    for (int r = 0; r < 32; r += 8)
        outp[(size_t)(nb + ty8 + r) * K + kb + tx] = f2bs(tile[tx][ty8 + r]);
}

// ---------------- MFMA GEMM: out = act(A[MxK] @ B + bias)(+residual) ----------------
// BT is bf16 [N][K] (pre-transposed). M,N multiples of 128; K multiple of 32.
// TA in {float, short(bf16 bits)}, TO in {float, bf16}. act: 0 none, 1 gelu, 2 softplus.
template<typename TA, typename TO>
__global__ __launch_bounds__(256) void mfma_gemm(const TA* __restrict__ A,
        const short* __restrict__ BT, const float* __restrict__ bias,
        const float* __restrict__ residual, TO* __restrict__ out,
        int M, int N, int K, int act)
{
    __shared__ __align__(16) short As[128 * 40];   // row m: As[m*40 + k], k=0..31
    __shared__ __align__(16) short Bs[128 * 40];   // row n: Bs[n*40 + k]
    int m0 = blockIdx.y * 128, n0 = blockIdx.x * 128;
    int tid = threadIdx.x;
    int w = tid >> 6, lane = tid & 63;
    int wm = (w >> 1) * 64, wn = (w & 1) * 64;
    int lm = lane & 15, quad = lane >> 4;
    floatx4 acc[4][4];
    #pragma unroll
    for (int i = 0; i < 4; ++i)
        #pragma unroll
        for (int j = 0; j < 4; ++j)
            acc[i][j] = (floatx4){0.f, 0.f, 0.f, 0.f};

    int sr = tid >> 3;          // 0..31
    int kq = (tid & 7) * 4;     // 0,4,...,28

    for (int kt = 0; kt < K; kt += 32) {
        #pragma unroll
        for (int r = 0; r < 4; ++r) {
            int m = sr + r * 32;
            short4 pk = ld4bf(A + (size_t)(m0 + m) * K + kt + kq);
            *(short4*)&As[m * 40 + kq] = pk;
        }
        #pragma unroll
        for (int r = 0; r < 4; ++r) {
            int n = sr + r * 32;
            short4 pk = *(const short4*)(BT + (size_t)(n0 + n) * K + kt + kq);
            *(short4*)&Bs[n * 40 + kq] = pk;
        }
        __syncthreads();
        short8 af[4], bfr[4];
        #pragma unroll
        for (int i = 0; i < 4; ++i) af[i]  = *(const short8*)&As[(wm + i * 16 + lm) * 40 + quad * 8];
        #pragma unroll
        for (int j = 0; j < 4; ++j) bfr[j] = *(const short8*)&Bs[(wn + j * 16 + lm) * 40 + quad * 8];
        #pragma unroll
        for (int i = 0; i < 4; ++i)
            #pragma unroll
            for (int j = 0; j < 4; ++j)
                acc[i][j] = __builtin_amdgcn_mfma_f32_16x16x32_bf16(af[i], bfr[j], acc[i][j], 0, 0, 0);
        __syncthreads();
    }

    #pragma unroll
    for (int i = 0; i < 4; ++i) {
        int gmb = m0 + wm + i * 16 + quad * 4;
        #pragma unroll
        for (int j = 0; j < 4; ++j) {
            int gn = n0 + wn + j * 16 + lm;
            float bia = bias[gn];
            #pragma unroll
            for (int reg = 0; reg < 4; ++reg) {
                int gm = gmb + reg;
                float v = acc[i][j][reg] + bia;
                if (act == 1)      v = 0.5f * v * (1.f + erff(v * 0.7071067811865476f));
                else if (act == 2) v = (v > 20.f) ? v : log1pf(__expf(v));
                if (residual) v += residual[(size_t)gm * N + gn];
                stO(out, (size_t)gm * N + gn, v);
            }
        }
    }
}

// ---------------- stage A: day-scale + gauss conv + patch LN(8192) ----------------
__global__ void patch_kernel(const float* __restrict__ x, const float* __restrict__ dw,
                             const float* __restrict__ db, const float* __restrict__ gk,
                             const float* __restrict__ g1, const float* __restrict__ b1,
                             const int* __restrict__ day_idx, bf16* __restrict__ pe_v)
{
    __shared__ float xs[51][256];
    int blk = blockIdx.x;
    int b = blk >> 8, p = blk & 255;
    int f = threadIdx.x;
    int di = day_idx[b];
    float w  = dw[di * NFEAT + f];
    float bb = db[di * NFEAT + f];
    int t0 = p * KL - 10;
    for (int r = 0; r < 51; ++r) {
        int t = t0 + r;
        xs[r][f] = (t >= 0 && t < TLEN) ? x[((size_t)b * TLEN + t) * NFEAT + f] * w + bb : 0.f;
    }
    float gkr[20];
    #pragma unroll
    for (int k = 0; k < 20; ++k) gkr[k] = gk[f * 20 + k];
    __syncthreads();

    float c[32];
    float sum = 0.f, sumsq = 0.f;
    #pragma unroll
    for (int i = 0; i < 32; ++i) {
        float acc = 0.f;
        #pragma unroll
        for (int k = 0; k < 20; ++k) acc += xs[i + k][f] * gkr[k];
        c[i] = acc; sum += acc; sumsq += acc * acc;
    }
    blk_red_sum2(sum, sumsq);
    float mean = sum * (1.f / 8192.f);
    float var  = sumsq * (1.f / 8192.f) - mean * mean;
    float rstd = rsqrtf(fmaxf(var, 0.f) + 1e-6f);
    bf16* outp = pe_v + (size_t)blk * 8192;
    #pragma unroll
    for (int i = 0; i < 32; ++i) {
        int e = i * 256 + f;
        outp[e] = __float2bfloat16((c[i] - mean) * rstd * g1[e] + b1[e]);
    }
}

// ---------------- fallback / small-N VALU GEMM ----------------
#define BM 64
#define BN 64
#define BKK 16
template<typename TA>
__global__ void gemm_kernel(const TA* __restrict__ A, const float* __restrict__ Bw,
                            const float* __restrict__ bias, const float* __restrict__ residual,
                            float* __restrict__ outF, bf16* __restrict__ outB,
                            int M, int N, int K, int act)
{
    __shared__ float As[BKK][BM + 4];
    __shared__ float Bs[BKK][BN + 4];
    int n0 = blockIdx.x * BN, m0 = blockIdx.y * BM;
    int tid = threadIdx.x;
    int tx = tid & 15, ty = tid >> 4;
    float acc[4][4] = {};
    for (int k0 = 0; k0 < K; k0 += BKK) {
        for (int i = tid; i < BM * BKK; i += 256) {
            int m = i >> 4, k = i & 15;
            As[k][m] = ldA(A, (size_t)(m0 + m) * K + k0 + k);
        }
        for (int i = tid; i < BKK * BN; i += 256) {
            int k = i >> 6, n = i & 63;
            int gn = n0 + n;
            Bs[k][n] = (gn < N) ? Bw[(size_t)(k0 + k) * N + gn] : 0.f;
        }
        __syncthreads();
        #pragma unroll
        for (int k = 0; k < BKK; ++k) {
            float a[4], bb[4];
            #pragma unroll
            for (int i = 0; i < 4; ++i) a[i] = As[k][ty * 4 + i];
            #pragma unroll
            for (int j = 0; j < 4; ++j) bb[j] = Bs[k][tx * 4 + j];
            #pragma unroll
            for (int i = 0; i < 4; ++i)
                #pragma unroll
                for (int j = 0; j < 4; ++j) acc[i][j] += a[i] * bb[j];
        }
        __syncthreads();
    }
    #pragma unroll
    for (int i = 0; i < 4; ++i) {
        int m = m0 + ty * 4 + i;
        #pragma unroll
        for (int j = 0; j < 4; ++j) {
            int n = n0 + tx * 4 + j;
            if (n >= N) continue;
            float v = acc[i][j];
            v += bias[n];
            if (act == 1)      v = 0.5f * v * (1.f + erff(v * 0.7071067811865476f));
            else if (act == 2) v = (v > 20.f) ? v : log1pf(__expf(v));
            if (residual) v += residual[(size_t)m * N + n];
            if (outB) stO(outB, (size_t)m * N + n, v);
            else      stO(outF, (size_t)m * N + n, v);
        }
    }
}

// ---------------- LayerNorm over dim 512 ----------------
__global__ void ln_kernel(const float* __restrict__ in, const float* __restrict__ g,
                          const float* __restrict__ bta, float* __restrict__ out, float eps)
{
    int row = blockIdx.x, tid = threadIdx.x;
    const float* r = in + (size_t)row * DM;
    float v0 = r[tid], v1 = r[tid + 256];
    float s1 = v0 + v1, s2 = v0 * v0 + v1 * v1;
    blk_red_sum2(s1, s2);
    float mean = s1 * (1.f / 512.f);
    float var  = s2 * (1.f / 512.f) - mean * mean;
    float rstd = rsqrtf(fmaxf(var, 0.f) + eps);
    float* o = out + (size_t)row * DM;
    o[tid]       = (v0 - mean) * rstd * g[tid]       + bta[tid];
    o[tid + 256] = (v1 - mean) * rstd * g[tid + 256] + bta[tid + 256];
}

// ---------------- attention: one block per (b,h,q) ----------------
__global__ void attn_kernel(const float* __restrict__ qkv, const float* __restrict__ rel_table,
                            float* __restrict__ attno)
{
    __shared__ float qv[64];
    __shared__ float sc[256];
    __shared__ float rb[256];
    __shared__ float op[4][64];
    int blk = blockIdx.x;
    int q = blk & 255, bh = blk >> 8;
    int hh = bh & 7, b = bh >> 3;
    int tid = threadIdx.x;
    const float* base = qkv + (size_t)b * 256 * 1536;
    if (tid < 64) qv[tid] = base[(size_t)q * 1536 + hh * 64 + tid];
    __syncthreads();
    const float* krow = base + (size_t)tid * 1536 + 512 + hh * 64;
    float d = 0.f;
    #pragma unroll 16
    for (int i = 0; i < 64; ++i) d += qv[i] * krow[i];
    float s = d * 0.125f;
    int rel = tid - q; rel = rel < -128 ? -128 : (rel > 128 ? 128 : rel);
    s += rel_table[hh * 257 + rel + 128];
    if (tid > q) s += -1e9f;
    sc[tid] = s; rb[tid] = s;
    __syncthreads();
    for (int st = 128; st > 0; st >>= 1) { if (tid < st) rb[tid] = fmaxf(rb[tid], rb[tid + st]); __syncthreads(); }
    float mx = rb[0];
    __syncthreads();
    float e = __expf(s - mx);
    sc[tid] = e; rb[tid] = e;
    __syncthreads();
    for (int st = 128; st > 0; st >>= 1) { if (tid < st) rb[tid] += rb[tid + st]; __syncthreads(); }
    float inv = 1.f / rb[0];
    __syncthreads();
    int dd = tid & 63, c = tid >> 6;
    const float* vbase = base + 1024 + hh * 64 + dd;
    float o = 0.f;
    for (int k = c * 64; k < c * 64 + 64; ++k) o += sc[k] * vbase[(size_t)k * 1536];
    op[c][dd] = o;
    __syncthreads();
    if (tid < 64) {
        float r = (op[0][tid] + op[1][tid] + op[2][tid] + op[3][tid]) * inv;
        attno[((size_t)(b * 256 + q)) * DM + hh * 64 + tid] = r;
    }
}

// ---------------- mamba depthwise conv (k=4 causal) + silu ----------------
__global__ void mamba_conv_kernel(const bf16* __restrict__ xz, const float* __restrict__ cW,
                                  const float* __restrict__ cb, bf16* __restrict__ xc)
{
    int row = blockIdx.x;
    int b = row >> 8, t = row & 255;
    int tid = threadIdx.x;
    #pragma unroll
    for (int j = 0; j < 4; ++j) {
        int dd = tid + j * 256;
        float acc = cb[dd];
        #pragma unroll
        for (int k = 0; k < 4; ++k) {
            int ts = t - 3 + k;
            if (ts >= 0) acc += b2f(xz[((size_t)(b * 256 + ts)) * 2048 + dd]) * cW[dd * 4 + k];
        }
        xc[(size_t)row * DI + dd] = __float2bfloat16(acc * (1.f / (1.f + __expf(-acc))));
    }
}

// ---------------- selective scan ----------------
__global__ void scan_kernel(const float* __restrict__ delta, const bf16* __restrict__ xcv,
                            const float* __restrict__ bc, const bf16* __restrict__ xz,
                            const float* __restrict__ Alog, const float* __restrict__ Dp,
                            float* __restrict__ y)
{
    int blk = blockIdx.x;
    int b = blk >> 6, chunk = blk & 63;
    int tid = threadIdx.x;
    int s = tid & 15, dl = tid >> 4;
    int d = chunk * 16 + dl;
    float A  = -__expf(Alog[d * DST + s]);
    float Dv = Dp[d];
    float h = 0.f;
    for (int t = 0; t < 256; ++t) {
        size_t r = (size_t)(b * 256 + t);
        float dt = delta[r * DI + d];
        float u  = b2f(xcv[r * DI + d]);
        float Bv = bc[r * 32 + s];
        float Cv = bc[r * 32 + 16 + s];
        h = __expf(dt * A) * h + dt * Bv * u;
        float contrib = h * Cv;
        contrib += __shfl_xor(contrib, 1, 64);
        contrib += __shfl_xor(contrib, 2, 64);
        contrib += __shfl_xor(contrib, 4, 64);
        contrib += __shfl_xor(contrib, 8, 64);
        if (s == 0) {
            float z = b2f(xz[r * 2048 + DI + d]);
            y[r * DI + d] = (contrib + u * Dv) * (z * (1.f / (1.f + __expf(-z))));
        }
    }
}

// ---------------- host helpers ----------------
template<typename TA>
static inline void launch_gemm(hipStream_t st, const TA* A, const float* Bw, const float* bias,
                               const float* res, float* outF, bf16* outB, int M, int N, int K, int act)
{
    dim3 grid((N + BN - 1) / BN, M / BM);
    gemm_kernel<TA><<<grid, 256, 0, st>>>(A, Bw, bias, res, outF, outB, M, N, K, act);
}

template<typename TA, typename TO>
static inline void launch_mfma(hipStream_t st, const TA* A, const short* BT, const float* bias,
                               const float* res, TO* out, int M, int N, int K, int act)
{
    dim3 grid(N / 128, M / 128);
    mfma_gemm<TA, TO><<<grid, 256, 0, st>>>(A, BT, bias, res, out, M, N, K, act);
}

static inline void launch_transpose(hipStream_t st, const float* in, short* out,
                                    int K, int N, int layers, size_t in_ls, size_t out_ls)
{
    dim3 grid(N / 32, K / 32, layers);
    transpose_cvt<<<grid, 256, 0, st>>>(in, out, K, N, in_ls, out_ls);
}

extern "C" void kernel_launch(void* const* d_in, const int* in_sizes, int n_in,
                              void* d_out, int out_size, void* d_ws, size_t ws_size,
                              hipStream_t stream)
{
    const float* x_in     = (const float*)d_in[0];
    const float* day_w    = (const float*)d_in[1];
    const float* day_b    = (const float*)d_in[2];
    const float* gauss    = (const float*)d_in[3];
    const float* pe_ln1_g = (const float*)d_in[4];
    const float* pe_ln1_b = (const float*)d_in[5];
    const float* pe_W     = (const float*)d_in[6];
    const float* pe_b     = (const float*)d_in[7];
    const float* pe_ln2_g = (const float*)d_in[8];
    const float* pe_ln2_b = (const float*)d_in[9];
    const float* rel_tab  = (const float*)d_in[10];
    const float* tf_ln_g  = (const float*)d_in[11];
    const float* tf_ln_b  = (const float*)d_in[12];
    const float* tf_qkv_W = (const float*)d_in[13];
    const float* tf_qkv_b = (const float*)d_in[14];
    const float* tf_out_W = (const float*)d_in[15];
    const float* tf_out_b = (const float*)d_in[16];
    const float* tf_ffln_g= (const float*)d_in[17];
    const float* tf_ffln_b= (const float*)d_in[18];
    const float* tf_fc1_W = (const float*)d_in[19];
    const float* tf_fc1_b = (const float*)d_in[20];
    const float* tf_fc2_W = (const float*)d_in[21];
    const float* tf_fc2_b = (const float*)d_in[22];
    const float* mb_norm_g= (const float*)d_in[23];
    const float* mb_norm_b= (const float*)d_in[24];
    const float* mb_in_W  = (const float*)d_in[25];
    const float* mb_in_b  = (const float*)d_in[26];
    const float* mb_conv_W= (const float*)d_in[27];
    const float* mb_conv_b= (const float*)d_in[28];
    const float* mb_xp_W  = (const float*)d_in[29];
    const float* mb_xp_b  = (const float*)d_in[30];
    const float* mb_dt_W  = (const float*)d_in[31];
    const float* mb_dt_b  = (const float*)d_in[32];
    const float* mb_Alog  = (const float*)d_in[33];
    const float* mb_D     = (const float*)d_in[34];
    const float* mb_out_W = (const float*)d_in[35];
    const float* mb_out_b = (const float*)d_in[36];
    const float* head_W   = (const float*)d_in[37];
    const float* head_b   = (const float*)d_in[38];
    const int*   day_idx  = (const int*)d_in[39];

    bool big = ws_size >= ((size_t)59 << 20);

    if (big) {
        // ---- layout: wT 0-22MB | x_state 22-26 | arena 26+ (peak 58.25 MB) ----
        char* base = (char*)d_ws;
        short* wT = (short*)base;
        float* x_state = (float*)(base + ((size_t)22 << 20));
        char* arena = base + ((size_t)26 << 20);

        bf16*  pe_v  = (bf16*)arena;                           // 32 MB
        float* hbuf  = (float*)arena;                          // 4 MB
        float* qkvb  = (float*)(arena + ((size_t)4  << 20));   // 12 MB
        float* attno = (float*)(arena + ((size_t)16 << 20));   // 4 MB
        bf16*  ffb   = (bf16*) (arena + ((size_t)20 << 20));   // 8 MB
        bf16*  xzb   = (bf16*) (arena + ((size_t)4  << 20));   // 8 MB
        bf16*  xcb   = (bf16*) (arena + ((size_t)12 << 20));   // 4 MB
        float* deltab= (float*)(arena + ((size_t)16 << 20));   // 8 MB
        float* yb    = (float*)(arena + ((size_t)24 << 20));   // 8 MB
        float* bcb   = (float*)(arena + ((size_t)32 << 20));   // 0.25 MB

        // wT element offsets
        const size_t qkvT_o = 0,            qkvT_ls = (size_t)1536 * 512;
        const size_t outT_o = 1572864,      outT_ls = (size_t)512 * 512;
        const size_t fc1T_o = 2097152,      fc1T_ls = (size_t)2048 * 512;
        const size_t fc2T_o = 4194304,      fc2T_ls = (size_t)512 * 2048;
        const size_t inT_o  = 0,            inT_ls  = (size_t)2048 * 512;
        const size_t dtT_o  = 4194304,      dtT_ls  = (size_t)1024 * 1024;
        const size_t owT_o  = 8388608,      owT_ls  = (size_t)512 * 1024;

        // ---- stage A ----
        launch_transpose(stream, pe_W, wT, 8192, 512, 1, 0, 0);
        patch_kernel<<<MROWS, 256, 0, stream>>>(x_in, day_w, day_b, gauss, pe_ln1_g, pe_ln1_b,
                                                day_idx, pe_v);
        launch_mfma(stream, (const short*)pe_v, wT, pe_b, (const float*)nullptr, x_state,
                    MROWS, DM, KL * NFEAT, 0);
        ln_kernel<<<MROWS, 256, 0, stream>>>(x_state, pe_ln2_g, pe_ln2_b, x_state, 1e-6f);

        // ---- transformer weights ----
        launch_transpose(stream, tf_qkv_W, wT + qkvT_o, 512, 1536, 2, (size_t)512 * 1536, qkvT_ls);
        launch_transpose(stream, tf_out_W, wT + outT_o, 512, 512, 2, (size_t)512 * 512, outT_ls);
        launch_transpose(stream, tf_fc1_W, wT + fc1T_o, 512, 2048, 2, (size_t)512 * 2048, fc1T_ls);
        launch_transpose(stream, tf_fc2_W, wT + fc2T_o, 2048, 512, 2, (size_t)2048 * 512, fc2T_ls);

        for (int i = 0; i < 2; ++i) {
            ln_kernel<<<MROWS, 256, 0, stream>>>(x_state, tf_ln_g + i * DM, tf_ln_b + i * DM, hbuf, 1e-5f);
            launch_mfma(stream, hbuf, wT + qkvT_o + i * qkvT_ls, tf_qkv_b + i * 3 * DM,
                        (const float*)nullptr, qkvb, MROWS, 3 * DM, DM, 0);
            attn_kernel<<<BSZ * NHEAD_ * SP, 256, 0, stream>>>(qkvb, rel_tab, attno);
            launch_mfma(stream, attno, wT + outT_o + i * outT_ls, tf_out_b + i * DM,
                        x_state, x_state, MROWS, DM, DM, 0);
            ln_kernel<<<MROWS, 256, 0, stream>>>(x_state, tf_ffln_g + i * DM, tf_ffln_b + i * DM, hbuf, 1e-5f);
            launch_mfma(stream, hbuf, wT + fc1T_o + i * fc1T_ls, tf_fc1_b + i * FFD,
                        (const float*)nullptr, ffb, MROWS, FFD, DM, 1);
            launch_mfma(stream, (const short*)ffb, wT + fc2T_o + i * fc2T_ls, tf_fc2_b + i * DM,
                        x_state, x_state, MROWS, DM, FFD, 0);
        }

        // ---- mamba weights ----
        launch_transpose(stream, mb_in_W, wT + inT_o, 512, 2048, 4, (size_t)512 * 2048, inT_ls);
        launch_transpose(stream, mb_dt_W, wT + dtT_o, 1024, 1024, 4, (size_t)1024 * 1024, dtT_ls);
        launch_transpose(stream, mb_out_W, wT + owT_o, 1024, 512, 4, (size_t)1024 * 512, owT_ls);

        for (int i = 0; i < 4; ++i) {
            ln_kernel<<<MROWS, 256, 0, stream>>>(x_state, mb_norm_g + i * DM, mb_norm_b + i * DM, hbuf, 1e-5f);
            launch_mfma(stream, hbuf, wT + inT_o + i * inT_ls, mb_in_b + i * 2 * DI,
                        (const float*)nullptr, xzb, MROWS, 2 * DI, DM, 0);
            mamba_conv_kernel<<<MROWS, 256, 0, stream>>>(xzb, mb_conv_W + (size_t)i * DI * 4,
                                                         mb_conv_b + i * DI, xcb);
            launch_gemm(stream, xcb, mb_xp_W + (size_t)i * DI * 2 * DST, mb_xp_b + i * 2 * DST,
                        (const float*)nullptr, bcb, (bf16*)nullptr, MROWS, 2 * DST, DI, 0);
            launch_mfma(stream, (const short*)xcb, wT + dtT_o + i * dtT_ls, mb_dt_b + i * DI,
                        (const float*)nullptr, deltab, MROWS, DI, DI, 2);
            scan_kernel<<<BSZ * (DI / 16), 256, 0, stream>>>(deltab, xcb, bcb, xzb,
                                                             mb_Alog + (size_t)i * DI * DST,
                                                             mb_D + i * DI, yb);
            launch_mfma(stream, yb, wT + owT_o + i * owT_ls, mb_out_b + i * DM,
                        x_state, x_state, MROWS, DM, DI, 0);
        }

        launch_gemm(stream, x_state, head_W, head_b, (const float*)nullptr, (float*)d_out, (bf16*)nullptr,
                    MROWS, NPHD, DM, 0);
    } else {
        // ---- fallback: round-3 all-VALU path (peak 36.25 MB) ----
        char* base = (char*)d_ws;
        float* x_state = (float*)base;
        char* arena = base + ((size_t)4 << 20);
        bf16* pe_v = (bf16*)arena;
        float* hbuf  = (float*)arena;
        float* qkvb  = (float*)(arena + ((size_t)4  << 20));
        float* attno = (float*)(arena + ((size_t)16 << 20));
        bf16*  ffb   = (bf16*) (arena + ((size_t)20 << 20));
        bf16*  xzb   = (bf16*) (arena + ((size_t)4  << 20));
        bf16*  xcb   = (bf16*) (arena + ((size_t)12 << 20));
        float* deltab= (float*)(arena + ((size_t)16 << 20));
        float* yb    = (float*)(arena + ((size_t)24 << 20));
        float* bcb   = (float*)(arena + ((size_t)32 << 20));

        patch_kernel<<<MROWS, 256, 0, stream>>>(x_in, day_w, day_b, gauss, pe_ln1_g, pe_ln1_b,
                                                day_idx, pe_v);
        launch_gemm(stream, pe_v, pe_W, pe_b, (const float*)nullptr, x_state, (bf16*)nullptr,
                    MROWS, DM, KL * NFEAT, 0);
        ln_kernel<<<MROWS, 256, 0, stream>>>(x_state, pe_ln2_g, pe_ln2_b, x_state, 1e-6f);
        for (int i = 0; i < 2; ++i) {
            ln_kernel<<<MROWS, 256, 0, stream>>>(x_state, tf_ln_g + i * DM, tf_ln_b + i * DM, hbuf, 1e-5f);
            launch_gemm(stream, hbuf, tf_qkv_W + (size_t)i * DM * 3 * DM, tf_qkv_b + i * 3 * DM,
                        (const float*)nullptr, qkvb, (bf16*)nullptr, MROWS, 3 * DM, DM, 0);
            attn_kernel<<<BSZ * NHEAD_ * SP, 256, 0, stream>>>(qkvb, rel_tab, attno);
            launch_gemm(stream, attno, tf_out_W + (size_t)i * DM * DM, tf_out_b + i * DM,
                        x_state, x_state, (bf16*)nullptr, MROWS, DM, DM, 0);
            ln_kernel<<<MROWS, 256, 0, stream>>>(x_state, tf_ffln_g + i * DM, tf_ffln_b + i * DM, hbuf, 1e-5f);
            launch_gemm(stream, hbuf, tf_fc1_W + (size_t)i * DM * FFD, tf_fc1_b + i * FFD,
                        (const float*)nullptr, (float*)nullptr, ffb, MROWS, FFD, DM, 1);
            launch_gemm(stream, ffb, tf_fc2_W + (size_t)i * FFD * DM, tf_fc2_b + i * DM,
                        x_state, x_state, (bf16*)nullptr, MROWS, DM, FFD, 0);
        }
        for (int i = 0; i < 4; ++i) {
            ln_kernel<<<MROWS, 256, 0, stream>>>(x_state, mb_norm_g + i * DM, mb_norm_b + i * DM, hbuf, 1e-5f);
            launch_gemm(stream, hbuf, mb_in_W + (size_t)i * DM * 2 * DI, mb_in_b + i * 2 * DI,
                        (const float*)nullptr, (float*)nullptr, xzb, MROWS, 2 * DI, DM, 0);
            mamba_conv_kernel<<<MROWS, 256, 0, stream>>>(xzb, mb_conv_W + (size_t)i * DI * 4,
                                                         mb_conv_b + i * DI, xcb);
            launch_gemm(stream, xcb, mb_xp_W + (size_t)i * DI * 2 * DST, mb_xp_b + i * 2 * DST,
                        (const float*)nullptr, bcb, (bf16*)nullptr, MROWS, 2 * DST, DI, 0);
            launch_gemm(stream, xcb, mb_dt_W + (size_t)i * DI * DI, mb_dt_b + i * DI,
                        (const float*)nullptr, deltab, (bf16*)nullptr, MROWS, DI, DI, 2);
            scan_kernel<<<BSZ * (DI / 16), 256, 0, stream>>>(deltab, xcb, bcb, xzb,
                                                             mb_Alog + (size_t)i * DI * DST,
                                                             mb_D + i * DI, yb);
            launch_gemm(stream, yb, mb_out_W + (size_t)i * DI * DM, mb_out_b + i * DM,
                        x_state, x_state, (bf16*)nullptr, MROWS, DM, DI, 0);
        }
        launch_gemm(stream, x_state, head_W, head_b, (const float*)nullptr, (float*)d_out, (bf16*)nullptr,
                    MROWS, NPHD, DM, 0);
    }
}

// Round 6
// 3344.561 us; speedup vs baseline: 2.0493x; 1.1971x over previous
//
#include <hip/hip_runtime.h>
#include <hip/hip_bf16.h>
#include <math.h>

typedef __hip_bfloat16 bf16;
typedef __attribute__((ext_vector_type(8))) short short8;
typedef __attribute__((ext_vector_type(4))) float floatx4;

// ---------------- constants ----------------
#define BSZ   8
#define TLEN  8192
#define NFEAT 256
#define DM    512
#define NHEAD_ 8
#define HD    64
#define SP    256          // NPATCH
#define KL    32
#define FFD   2048
#define DI    1024
#define DST   16
#define NPHD  41
#define MROWS (BSZ*SP)     // 2048

__device__ __forceinline__ float b2f(bf16 v) { return __bfloat162float(v); }
__device__ __forceinline__ short f2bs(float f) {
    union { bf16 h; short s; } u; u.h = __float2bfloat16(f); return u.s;
}
__device__ __forceinline__ float bs2f(short s) {
    union { short s; bf16 h; } u; u.s = s; return __bfloat162float(u.h);
}

__device__ __forceinline__ float ldA(const float* p, size_t i) { return p[i]; }
__device__ __forceinline__ float ldA(const bf16* p, size_t i)  { return b2f(p[i]); }
__device__ __forceinline__ float ldA(const short* p, size_t i) { return bs2f(p[i]); }
__device__ __forceinline__ void stO(float* p, size_t i, float v) { p[i] = v; }
__device__ __forceinline__ void stO(bf16* p, size_t i, float v)  { p[i] = __float2bfloat16(v); }

// load 8 consecutive elems as bf16 bit-patterns (16B aligned source for short path)
__device__ __forceinline__ short8 ld8bf(const float* p) {
    float4 v0 = *(const float4*)p;
    float4 v1 = *(const float4*)(p + 4);
    short8 r;
    r[0] = f2bs(v0.x); r[1] = f2bs(v0.y); r[2] = f2bs(v0.z); r[3] = f2bs(v0.w);
    r[4] = f2bs(v1.x); r[5] = f2bs(v1.y); r[6] = f2bs(v1.z); r[7] = f2bs(v1.w);
    return r;
}
__device__ __forceinline__ short8 ld8bf(const short* p) {
    return *(const short8*)p;
}

// ---------------- block reduce (sum of two values) over 256 threads ----------------
__device__ __forceinline__ void blk_red_sum2(float& s1, float& s2) {
    __shared__ float buf1[4], buf2[4];
    #pragma unroll
    for (int off = 32; off > 0; off >>= 1) {
        s1 += __shfl_down(s1, off, 64);
        s2 += __shfl_down(s2, off, 64);
    }
    int lane = threadIdx.x & 63, w = threadIdx.x >> 6;
    __syncthreads();
    if (lane == 0) { buf1[w] = s1; buf2[w] = s2; }
    __syncthreads();
    s1 = buf1[0] + buf1[1] + buf1[2] + buf1[3];
    s2 = buf2[0] + buf2[1] + buf2[2] + buf2[3];
}

// ---------------- weight transpose+convert: in fp32 [K][N] -> out bf16 [N][K] ----------------
__global__ void transpose_cvt(const float* __restrict__ in, short* __restrict__ out,
                              int K, int N, size_t in_ls, size_t out_ls)
{
    __shared__ float tile[32][33];
    const float* inp = in + (size_t)blockIdx.z * in_ls;
    short* outp = out + (size_t)blockIdx.z * out_ls;
    int kb = blockIdx.y * 32, nb = blockIdx.x * 32;
    int tx = threadIdx.x & 31, ty8 = threadIdx.x >> 5;
    #pragma unroll
    for (int r = 0; r < 32; r += 8)
        tile[ty8 + r][tx] = inp[(size_t)(kb + ty8 + r) * N + nb + tx];
    __syncthreads();
    #pragma unroll
    for (int r = 0; r < 32; r += 8)
        outp[(size_t)(nb + ty8 + r) * K + kb + tx] = f2bs(tile[tx][ty8 + r]);
}

// ---------------- 64x64-tile MFMA GEMM ----------------
// out = act(A[MxK] @ B + bias)(+residual). BT is bf16 [N][K]. M,N mult of 64; K mult of 32.
template<typename TA, typename TO>
__global__ __launch_bounds__(256) void mfma_gemm64(const TA* __restrict__ A,
        const short* __restrict__ BT, const float* __restrict__ bias,
        const float* __restrict__ residual, TO* __restrict__ out,
        int M, int N, int K, int act)
{
    __shared__ __align__(16) short As[64 * 40];
    __shared__ __align__(16) short Bs[64 * 40];
    int m0 = blockIdx.y * 64, n0 = blockIdx.x * 64;
    int tid = threadIdx.x;
    int w = tid >> 6, lane = tid & 63;
    int wm = (w >> 1) * 32, wn = (w & 1) * 32;
    int lm = lane & 15, quad = lane >> 4;
    floatx4 acc[2][2];
    #pragma unroll
    for (int i = 0; i < 2; ++i)
        #pragma unroll
        for (int j = 0; j < 2; ++j)
            acc[i][j] = (floatx4){0.f, 0.f, 0.f, 0.f};

    int sr = tid >> 2;          // 0..63 row
    int kq = (tid & 3) * 8;     // 0,8,16,24

    for (int kt = 0; kt < K; kt += 32) {
        short8 av = ld8bf(A + (size_t)(m0 + sr) * K + kt + kq);
        short8 bv = *(const short8*)(BT + (size_t)(n0 + sr) * K + kt + kq);
        *(short8*)&As[sr * 40 + kq] = av;
        *(short8*)&Bs[sr * 40 + kq] = bv;
        __syncthreads();
        short8 af[2], bfr[2];
        #pragma unroll
        for (int i = 0; i < 2; ++i) af[i]  = *(const short8*)&As[(wm + i * 16 + lm) * 40 + quad * 8];
        #pragma unroll
        for (int j = 0; j < 2; ++j) bfr[j] = *(const short8*)&Bs[(wn + j * 16 + lm) * 40 + quad * 8];
        #pragma unroll
        for (int i = 0; i < 2; ++i)
            #pragma unroll
            for (int j = 0; j < 2; ++j)
                acc[i][j] = __builtin_amdgcn_mfma_f32_16x16x32_bf16(af[i], bfr[j], acc[i][j], 0, 0, 0);
        __syncthreads();
    }

    #pragma unroll
    for (int i = 0; i < 2; ++i) {
        int gmb = m0 + wm + i * 16 + quad * 4;
        #pragma unroll
        for (int j = 0; j < 2; ++j) {
            int gn = n0 + wn + j * 16 + lm;
            float bia = bias[gn];
            #pragma unroll
            for (int reg = 0; reg < 4; ++reg) {
                int gm = gmb + reg;
                float v = acc[i][j][reg] + bia;
                if (act == 1)      v = 0.5f * v * (1.f + erff(v * 0.7071067811865476f));
                else if (act == 2) v = (v > 20.f) ? v : log1pf(__expf(v));
                if (residual) v += residual[(size_t)gm * N + gn];
                stO(out, (size_t)gm * N + gn, v);
            }
        }
    }
}

// ---------------- skinny GEMM (small N): out = A[MxK] @ W[KxN] + bias ----------------
// block: 8 rows, 256 threads (n = tid&63, rh = tid>>6 handles rows rh, rh+4). grid M/8.
template<typename TA>
__global__ __launch_bounds__(256) void skinny_gemm(const TA* __restrict__ A,
        const float* __restrict__ W, const float* __restrict__ bias,
        float* __restrict__ out, int M, int N, int K)
{
    __shared__ float As[8][68];
    int m0 = blockIdx.x * 8;
    int tid = threadIdx.x;
    int n = tid & 63, rh = tid >> 6;
    float acc0 = 0.f, acc1 = 0.f;
    for (int k0 = 0; k0 < K; k0 += 64) {
        int idx = tid * 2;
        int row = idx >> 6, kk = idx & 63;
        As[row][kk]     = ldA(A, (size_t)(m0 + row) * K + k0 + kk);
        As[row][kk + 1] = ldA(A, (size_t)(m0 + row) * K + k0 + kk + 1);
        __syncthreads();
        if (n < N) {
            for (int kk2 = 0; kk2 < 64; ++kk2) {
                float wv = W[(size_t)(k0 + kk2) * N + n];
                acc0 += As[rh][kk2] * wv;
                acc1 += As[rh + 4][kk2] * wv;
            }
        }
        __syncthreads();
    }
    if (n < N) {
        float bia = bias[n];
        out[(size_t)(m0 + rh) * N + n]     = acc0 + bia;
        out[(size_t)(m0 + rh + 4) * N + n] = acc1 + bia;
    }
}

// ---------------- stage A: day-scale + gauss conv + patch LN(8192) ----------------
__global__ void patch_kernel(const float* __restrict__ x, const float* __restrict__ dw,
                             const float* __restrict__ db, const float* __restrict__ gk,
                             const float* __restrict__ g1, const float* __restrict__ b1,
                             const int* __restrict__ day_idx, bf16* __restrict__ pe_v)
{
    __shared__ float xs[51][256];
    int blk = blockIdx.x;
    int b = blk >> 8, p = blk & 255;
    int f = threadIdx.x;
    int di = day_idx[b];
    float w  = dw[di * NFEAT + f];
    float bb = db[di * NFEAT + f];
    int t0 = p * KL - 10;
    for (int r = 0; r < 51; ++r) {
        int t = t0 + r;
        xs[r][f] = (t >= 0 && t < TLEN) ? x[((size_t)b * TLEN + t) * NFEAT + f] * w + bb : 0.f;
    }
    float gkr[20];
    #pragma unroll
    for (int k = 0; k < 20; ++k) gkr[k] = gk[f * 20 + k];
    __syncthreads();

    float c[32];
    float sum = 0.f, sumsq = 0.f;
    #pragma unroll
    for (int i = 0; i < 32; ++i) {
        float acc = 0.f;
        #pragma unroll
        for (int k = 0; k < 20; ++k) acc += xs[i + k][f] * gkr[k];
        c[i] = acc; sum += acc; sumsq += acc * acc;
    }
    blk_red_sum2(sum, sumsq);
    float mean = sum * (1.f / 8192.f);
    float var  = sumsq * (1.f / 8192.f) - mean * mean;
    float rstd = rsqrtf(fmaxf(var, 0.f) + 1e-6f);
    bf16* outp = pe_v + (size_t)blk * 8192;
    #pragma unroll
    for (int i = 0; i < 32; ++i) {
        int e = i * 256 + f;
        outp[e] = __float2bfloat16((c[i] - mean) * rstd * g1[e] + b1[e]);
    }
}

// ---------------- fallback VALU GEMM ----------------
#define BM 64
#define BN 64
#define BKK 16
template<typename TA>
__global__ void gemm_kernel(const TA* __restrict__ A, const float* __restrict__ Bw,
                            const float* __restrict__ bias, const float* __restrict__ residual,
                            float* __restrict__ outF, bf16* __restrict__ outB,
                            int M, int N, int K, int act)
{
    __shared__ float As[BKK][BM + 4];
    __shared__ float Bs[BKK][BN + 4];
    int n0 = blockIdx.x * BN, m0 = blockIdx.y * BM;
    int tid = threadIdx.x;
    int tx = tid & 15, ty = tid >> 4;
    float acc[4][4] = {};
    for (int k0 = 0; k0 < K; k0 += BKK) {
        for (int i = tid; i < BM * BKK; i += 256) {
            int m = i >> 4, k = i & 15;
            As[k][m] = ldA(A, (size_t)(m0 + m) * K + k0 + k);
        }
        for (int i = tid; i < BKK * BN; i += 256) {
            int k = i >> 6, n = i & 63;
            int gn = n0 + n;
            Bs[k][n] = (gn < N) ? Bw[(size_t)(k0 + k) * N + gn] : 0.f;
        }
        __syncthreads();
        #pragma unroll
        for (int k = 0; k < BKK; ++k) {
            float a[4], bb[4];
            #pragma unroll
            for (int i = 0; i < 4; ++i) a[i] = As[k][ty * 4 + i];
            #pragma unroll
            for (int j = 0; j < 4; ++j) bb[j] = Bs[k][tx * 4 + j];
            #pragma unroll
            for (int i = 0; i < 4; ++i)
                #pragma unroll
                for (int j = 0; j < 4; ++j) acc[i][j] += a[i] * bb[j];
        }
        __syncthreads();
    }
    #pragma unroll
    for (int i = 0; i < 4; ++i) {
        int m = m0 + ty * 4 + i;
        #pragma unroll
        for (int j = 0; j < 4; ++j) {
            int n = n0 + tx * 4 + j;
            if (n >= N) continue;
            float v = acc[i][j];
            v += bias[n];
            if (act == 1)      v = 0.5f * v * (1.f + erff(v * 0.7071067811865476f));
            else if (act == 2) v = (v > 20.f) ? v : log1pf(__expf(v));
            if (residual) v += residual[(size_t)m * N + n];
            if (outB) stO(outB, (size_t)m * N + n, v);
            else      stO(outF, (size_t)m * N + n, v);
        }
    }
}

// ---------------- LayerNorm over dim 512 ----------------
__global__ void ln_kernel(const float* __restrict__ in, const float* __restrict__ g,
                          const float* __restrict__ bta, float* __restrict__ out, float eps)
{
    int row = blockIdx.x, tid = threadIdx.x;
    const float* r = in + (size_t)row * DM;
    float v0 = r[tid], v1 = r[tid + 256];
    float s1 = v0 + v1, s2 = v0 * v0 + v1 * v1;
    blk_red_sum2(s1, s2);
    float mean = s1 * (1.f / 512.f);
    float var  = s2 * (1.f / 512.f) - mean * mean;
    float rstd = rsqrtf(fmaxf(var, 0.f) + eps);
    float* o = out + (size_t)row * DM;
    o[tid]       = (v0 - mean) * rstd * g[tid]       + bta[tid];
    o[tid + 256] = (v1 - mean) * rstd * g[tid + 256] + bta[tid + 256];
}

// ---------------- attention v2: 32 q-rows per block, LDS-staged K/V ----------------
__global__ __launch_bounds__(256) void attn_kernel2(const float* __restrict__ qkv,
        const float* __restrict__ rel_table, float* __restrict__ attno)
{
    __shared__ float Qs[32][68];
    __shared__ float KVs[64 * 65];
    __shared__ float Ss[32][260];
    __shared__ float Ls[32];
    int blk = blockIdx.x;
    int qc = blk & 7; int bh = blk >> 3; int h = bh & 7; int b = bh >> 3;
    int q0 = qc * 32;
    int tid = threadIdx.x;
    const float* base = qkv + (size_t)b * 256 * 1536;
    for (int idx = tid; idx < 2048; idx += 256) {
        int q = idx >> 6, d = idx & 63;
        Qs[q][d] = base[(size_t)(q0 + q) * 1536 + h * 64 + d];
    }
    int tq = tid >> 3, kl = tid & 7;
    float mx = -3e38f;
    for (int kc = 0; kc < 4; ++kc) {
        __syncthreads();
        for (int idx = tid; idx < 4096; idx += 256) {
            int kk = idx >> 6, d = idx & 63;
            KVs[kk * 65 + d] = base[(size_t)(kc * 64 + kk) * 1536 + 512 + h * 64 + d];
        }
        __syncthreads();
        #pragma unroll
        for (int j = 0; j < 8; ++j) {
            int kk = kl * 8 + j;
            int gk = kc * 64 + kk;
            float dsum = 0.f;
            #pragma unroll 16
            for (int d = 0; d < 64; ++d) dsum += Qs[tq][d] * KVs[kk * 65 + d];
            float s = dsum * 0.125f;
            int gq = q0 + tq;
            int rel = gk - gq; rel = rel < -128 ? -128 : (rel > 128 ? 128 : rel);
            s += rel_table[h * 257 + rel + 128];
            if (gk > gq) s -= 1e9f;
            Ss[tq][gk] = s;
            mx = fmaxf(mx, s);
        }
    }
    mx = fmaxf(mx, __shfl_xor(mx, 1, 64));
    mx = fmaxf(mx, __shfl_xor(mx, 2, 64));
    mx = fmaxf(mx, __shfl_xor(mx, 4, 64));
    float lsum = 0.f;
    for (int kc = 0; kc < 4; ++kc) {
        #pragma unroll
        for (int j = 0; j < 8; ++j) {
            int gk = kc * 64 + kl * 8 + j;
            float e = __expf(Ss[tq][gk] - mx);
            Ss[tq][gk] = e;
            lsum += e;
        }
    }
    lsum += __shfl_xor(lsum, 1, 64);
    lsum += __shfl_xor(lsum, 2, 64);
    lsum += __shfl_xor(lsum, 4, 64);
    if (kl == 0) Ls[tq] = 1.f / lsum;

    float o[8] = {};
    for (int kc = 0; kc < 4; ++kc) {
        __syncthreads();
        for (int idx = tid; idx < 4096; idx += 256) {
            int kk = idx >> 6, d = idx & 63;
            KVs[kk * 65 + d] = base[(size_t)(kc * 64 + kk) * 1536 + 1024 + h * 64 + d];
        }
        __syncthreads();
        for (int kk = 0; kk < 64; ++kk) {
            float p = Ss[tq][kc * 64 + kk];
            #pragma unroll
            for (int dj = 0; dj < 8; ++dj)
                o[dj] += p * KVs[kk * 65 + kl * 8 + dj];
        }
    }
    float inv = Ls[tq];
    #pragma unroll
    for (int dj = 0; dj < 8; ++dj)
        attno[(size_t)(b * 256 + q0 + tq) * DM + h * 64 + kl * 8 + dj] = o[dj] * inv;
}

// ---------------- old attention (fallback path) ----------------
__global__ void attn_kernel(const float* __restrict__ qkv, const float* __restrict__ rel_table,
                            float* __restrict__ attno)
{
    __shared__ float qv[64];
    __shared__ float sc[256];
    __shared__ float rb[256];
    __shared__ float op[4][64];
    int blk = blockIdx.x;
    int q = blk & 255, bh = blk >> 8;
    int hh = bh & 7, b = bh >> 3;
    int tid = threadIdx.x;
    const float* base = qkv + (size_t)b * 256 * 1536;
    if (tid < 64) qv[tid] = base[(size_t)q * 1536 + hh * 64 + tid];
    __syncthreads();
    const float* krow = base + (size_t)tid * 1536 + 512 + hh * 64;
    float d = 0.f;
    #pragma unroll 16
    for (int i = 0; i < 64; ++i) d += qv[i] * krow[i];
    float s = d * 0.125f;
    int rel = tid - q; rel = rel < -128 ? -128 : (rel > 128 ? 128 : rel);
    s += rel_table[hh * 257 + rel + 128];
    if (tid > q) s += -1e9f;
    sc[tid] = s; rb[tid] = s;
    __syncthreads();
    for (int st = 128; st > 0; st >>= 1) { if (tid < st) rb[tid] = fmaxf(rb[tid], rb[tid + st]); __syncthreads(); }
    float mx = rb[0];
    __syncthreads();
    float e = __expf(s - mx);
    sc[tid] = e; rb[tid] = e;
    __syncthreads();
    for (int st = 128; st > 0; st >>= 1) { if (tid < st) rb[tid] += rb[tid + st]; __syncthreads(); }
    float inv = 1.f / rb[0];
    __syncthreads();
    int dd = tid & 63, c = tid >> 6;
    const float* vbase = base + 1024 + hh * 64 + dd;
    float o = 0.f;
    for (int k = c * 64; k < c * 64 + 64; ++k) o += sc[k] * vbase[(size_t)k * 1536];
    op[c][dd] = o;
    __syncthreads();
    if (tid < 64) {
        float r = (op[0][tid] + op[1][tid] + op[2][tid] + op[3][tid]) * inv;
        attno[((size_t)(b * 256 + q)) * DM + hh * 64 + tid] = r;
    }
}

// ---------------- mamba depthwise conv (k=4 causal) + silu ----------------
__global__ void mamba_conv_kernel(const bf16* __restrict__ xz, const float* __restrict__ cW,
                                  const float* __restrict__ cb, bf16* __restrict__ xc)
{
    int row = blockIdx.x;
    int b = row >> 8, t = row & 255;
    int tid = threadIdx.x;
    #pragma unroll
    for (int j = 0; j < 4; ++j) {
        int dd = tid + j * 256;
        float acc = cb[dd];
        #pragma unroll
        for (int k = 0; k < 4; ++k) {
            int ts = t - 3 + k;
            if (ts >= 0) acc += b2f(xz[((size_t)(b * 256 + ts)) * 2048 + dd]) * cW[dd * 4 + k];
        }
        xc[(size_t)row * DI + dd] = __float2bfloat16(acc * (1.f / (1.f + __expf(-acc))));
    }
}

// ---------------- selective scan ----------------
__global__ void scan_kernel(const float* __restrict__ delta, const bf16* __restrict__ xcv,
                            const float* __restrict__ bc, const bf16* __restrict__ xz,
                            const float* __restrict__ Alog, const float* __restrict__ Dp,
                            float* __restrict__ y)
{
    int blk = blockIdx.x;
    int b = blk >> 6, chunk = blk & 63;
    int tid = threadIdx.x;
    int s = tid & 15, dl = tid >> 4;
    int d = chunk * 16 + dl;
    float A  = -__expf(Alog[d * DST + s]);
    float Dv = Dp[d];
    float h = 0.f;
    for (int t = 0; t < 256; ++t) {
        size_t r = (size_t)(b * 256 + t);
        float dt = delta[r * DI + d];
        float u  = b2f(xcv[r * DI + d]);
        float Bv = bc[r * 32 + s];
        float Cv = bc[r * 32 + 16 + s];
        h = __expf(dt * A) * h + dt * Bv * u;
        float contrib = h * Cv;
        contrib += __shfl_xor(contrib, 1, 64);
        contrib += __shfl_xor(contrib, 2, 64);
        contrib += __shfl_xor(contrib, 4, 64);
        contrib += __shfl_xor(contrib, 8, 64);
        if (s == 0) {
            float z = b2f(xz[r * 2048 + DI + d]);
            y[r * DI + d] = (contrib + u * Dv) * (z * (1.f / (1.f + __expf(-z))));
        }
    }
}

// ---------------- host helpers ----------------
template<typename TA>
static inline void launch_gemm(hipStream_t st, const TA* A, const float* Bw, const float* bias,
                               const float* res, float* outF, bf16* outB, int M, int N, int K, int act)
{
    dim3 grid((N + BN - 1) / BN, M / BM);
    gemm_kernel<TA><<<grid, 256, 0, st>>>(A, Bw, bias, res, outF, outB, M, N, K, act);
}

template<typename TA, typename TO>
static inline void launch_mfma(hipStream_t st, const TA* A, const short* BT, const float* bias,
                               const float* res, TO* out, int M, int N, int K, int act)
{
    dim3 grid(N / 64, M / 64);
    mfma_gemm64<TA, TO><<<grid, 256, 0, st>>>(A, BT, bias, res, out, M, N, K, act);
}

static inline void launch_transpose(hipStream_t st, const float* in, short* out,
                                    int K, int N, int layers, size_t in_ls, size_t out_ls)
{
    dim3 grid(N / 32, K / 32, layers);
    transpose_cvt<<<grid, 256, 0, st>>>(in, out, K, N, in_ls, out_ls);
}

extern "C" void kernel_launch(void* const* d_in, const int* in_sizes, int n_in,
                              void* d_out, int out_size, void* d_ws, size_t ws_size,
                              hipStream_t stream)
{
    const float* x_in     = (const float*)d_in[0];
    const float* day_w    = (const float*)d_in[1];
    const float* day_b    = (const float*)d_in[2];
    const float* gauss    = (const float*)d_in[3];
    const float* pe_ln1_g = (const float*)d_in[4];
    const float* pe_ln1_b = (const float*)d_in[5];
    const float* pe_W     = (const float*)d_in[6];
    const float* pe_b     = (const float*)d_in[7];
    const float* pe_ln2_g = (const float*)d_in[8];
    const float* pe_ln2_b = (const float*)d_in[9];
    const float* rel_tab  = (const float*)d_in[10];
    const float* tf_ln_g  = (const float*)d_in[11];
    const float* tf_ln_b  = (const float*)d_in[12];
    const float* tf_qkv_W = (const float*)d_in[13];
    const float* tf_qkv_b = (const float*)d_in[14];
    const float* tf_out_W = (const float*)d_in[15];
    const float* tf_out_b = (const float*)d_in[16];
    const float* tf_ffln_g= (const float*)d_in[17];
    const float* tf_ffln_b= (const float*)d_in[18];
    const float* tf_fc1_W = (const float*)d_in[19];
    const float* tf_fc1_b = (const float*)d_in[20];
    const float* tf_fc2_W = (const float*)d_in[21];
    const float* tf_fc2_b = (const float*)d_in[22];
    const float* mb_norm_g= (const float*)d_in[23];
    const float* mb_norm_b= (const float*)d_in[24];
    const float* mb_in_W  = (const float*)d_in[25];
    const float* mb_in_b  = (const float*)d_in[26];
    const float* mb_conv_W= (const float*)d_in[27];
    const float* mb_conv_b= (const float*)d_in[28];
    const float* mb_xp_W  = (const float*)d_in[29];
    const float* mb_xp_b  = (const float*)d_in[30];
    const float* mb_dt_W  = (const float*)d_in[31];
    const float* mb_dt_b  = (const float*)d_in[32];
    const float* mb_Alog  = (const float*)d_in[33];
    const float* mb_D     = (const float*)d_in[34];
    const float* mb_out_W = (const float*)d_in[35];
    const float* mb_out_b = (const float*)d_in[36];
    const float* head_W   = (const float*)d_in[37];
    const float* head_b   = (const float*)d_in[38];
    const int*   day_idx  = (const int*)d_in[39];

    bool big = ws_size >= ((size_t)59 << 20);

    if (big) {
        char* base = (char*)d_ws;
        short* wT = (short*)base;
        float* x_state = (float*)(base + ((size_t)22 << 20));
        char* arena = base + ((size_t)26 << 20);

        bf16*  pe_v  = (bf16*)arena;                           // 32 MB
        float* hbuf  = (float*)arena;                          // 4 MB
        float* qkvb  = (float*)(arena + ((size_t)4  << 20));   // 12 MB
        float* attno = (float*)(arena + ((size_t)16 << 20));   // 4 MB
        bf16*  ffb   = (bf16*) (arena + ((size_t)20 << 20));   // 8 MB
        bf16*  xzb   = (bf16*) (arena + ((size_t)4  << 20));   // 8 MB
        bf16*  xcb   = (bf16*) (arena + ((size_t)12 << 20));   // 4 MB
        float* deltab= (float*)(arena + ((size_t)16 << 20));   // 8 MB
        float* yb    = (float*)(arena + ((size_t)24 << 20));   // 8 MB
        float* bcb   = (float*)(arena + ((size_t)32 << 20));   // 0.25 MB

        const size_t qkvT_o = 0,            qkvT_ls = (size_t)1536 * 512;
        const size_t outT_o = 1572864,      outT_ls = (size_t)512 * 512;
        const size_t fc1T_o = 2097152,      fc1T_ls = (size_t)2048 * 512;
        const size_t fc2T_o = 4194304,      fc2T_ls = (size_t)512 * 2048;
        const size_t inT_o  = 0,            inT_ls  = (size_t)2048 * 512;
        const size_t dtT_o  = 4194304,      dtT_ls  = (size_t)1024 * 1024;
        const size_t owT_o  = 8388608,      owT_ls  = (size_t)512 * 1024;

        // ---- stage A ----
        launch_transpose(stream, pe_W, wT, 8192, 512, 1, 0, 0);
        patch_kernel<<<MROWS, 256, 0, stream>>>(x_in, day_w, day_b, gauss, pe_ln1_g, pe_ln1_b,
                                                day_idx, pe_v);
        launch_mfma(stream, (const short*)pe_v, wT, pe_b, (const float*)nullptr, x_state,
                    MROWS, DM, KL * NFEAT, 0);
        ln_kernel<<<MROWS, 256, 0, stream>>>(x_state, pe_ln2_g, pe_ln2_b, x_state, 1e-6f);

        // ---- transformer weights ----
        launch_transpose(stream, tf_qkv_W, wT + qkvT_o, 512, 1536, 2, (size_t)512 * 1536, qkvT_ls);
        launch_transpose(stream, tf_out_W, wT + outT_o, 512, 512, 2, (size_t)512 * 512, outT_ls);
        launch_transpose(stream, tf_fc1_W, wT + fc1T_o, 512, 2048, 2, (size_t)512 * 2048, fc1T_ls);
        launch_transpose(stream, tf_fc2_W, wT + fc2T_o, 2048, 512, 2, (size_t)2048 * 512, fc2T_ls);

        for (int i = 0; i < 2; ++i) {
            ln_kernel<<<MROWS, 256, 0, stream>>>(x_state, tf_ln_g + i * DM, tf_ln_b + i * DM, hbuf, 1e-5f);
            launch_mfma(stream, hbuf, wT + qkvT_o + i * qkvT_ls, tf_qkv_b + i * 3 * DM,
                        (const float*)nullptr, qkvb, MROWS, 3 * DM, DM, 0);
            attn_kernel2<<<BSZ * NHEAD_ * 8, 256, 0, stream>>>(qkvb, rel_tab, attno);
            launch_mfma(stream, attno, wT + outT_o + i * outT_ls, tf_out_b + i * DM,
                        x_state, x_state, MROWS, DM, DM, 0);
            ln_kernel<<<MROWS, 256, 0, stream>>>(x_state, tf_ffln_g + i * DM, tf_ffln_b + i * DM, hbuf, 1e-5f);
            launch_mfma(stream, hbuf, wT + fc1T_o + i * fc1T_ls, tf_fc1_b + i * FFD,
                        (const float*)nullptr, ffb, MROWS, FFD, DM, 1);
            launch_mfma(stream, (const short*)ffb, wT + fc2T_o + i * fc2T_ls, tf_fc2_b + i * DM,
                        x_state, x_state, MROWS, DM, FFD, 0);
        }

        // ---- mamba weights ----
        launch_transpose(stream, mb_in_W, wT + inT_o, 512, 2048, 4, (size_t)512 * 2048, inT_ls);
        launch_transpose(stream, mb_dt_W, wT + dtT_o, 1024, 1024, 4, (size_t)1024 * 1024, dtT_ls);
        launch_transpose(stream, mb_out_W, wT + owT_o, 1024, 512, 4, (size_t)1024 * 512, owT_ls);

        for (int i = 0; i < 4; ++i) {
            ln_kernel<<<MROWS, 256, 0, stream>>>(x_state, mb_norm_g + i * DM, mb_norm_b + i * DM, hbuf, 1e-5f);
            launch_mfma(stream, hbuf, wT + inT_o + i * inT_ls, mb_in_b + i * 2 * DI,
                        (const float*)nullptr, xzb, MROWS, 2 * DI, DM, 0);
            mamba_conv_kernel<<<MROWS, 256, 0, stream>>>(xzb, mb_conv_W + (size_t)i * DI * 4,
                                                         mb_conv_b + i * DI, xcb);
            skinny_gemm<<<MROWS / 8, 256, 0, stream>>>((const short*)xcb,
                        mb_xp_W + (size_t)i * DI * 2 * DST, mb_xp_b + i * 2 * DST,
                        bcb, MROWS, 2 * DST, DI);
            launch_mfma(stream, (const short*)xcb, wT + dtT_o + i * dtT_ls, mb_dt_b + i * DI,
                        (const float*)nullptr, deltab, MROWS, DI, DI, 2);
            scan_kernel<<<BSZ * (DI / 16), 256, 0, stream>>>(deltab, xcb, bcb, xzb,
                                                             mb_Alog + (size_t)i * DI * DST,
                                                             mb_D + i * DI, yb);
            launch_mfma(stream, yb, wT + owT_o + i * owT_ls, mb_out_b + i * DM,
                        x_state, x_state, MROWS, DM, DI, 0);
        }

        skinny_gemm<<<MROWS / 8, 256, 0, stream>>>(x_state, head_W, head_b,
                    (float*)d_out, MROWS, NPHD, DM);
    } else {
        // ---- fallback: all-VALU path ----
        char* base = (char*)d_ws;
        float* x_state = (float*)base;
        char* arena = base + ((size_t)4 << 20);
        bf16* pe_v = (bf16*)arena;
        float* hbuf  = (float*)arena;
        float* qkvb  = (float*)(arena + ((size_t)4  << 20));
        float* attno = (float*)(arena + ((size_t)16 << 20));
        bf16*  ffb   = (bf16*) (arena + ((size_t)20 << 20));
        bf16*  xzb   = (bf16*) (arena + ((size_t)4  << 20));
        bf16*  xcb   = (bf16*) (arena + ((size_t)12 << 20));
        float* deltab= (float*)(arena + ((size_t)16 << 20));
        float* yb    = (float*)(arena + ((size_t)24 << 20));
        float* bcb   = (float*)(arena + ((size_t)32 << 20));

        patch_kernel<<<MROWS, 256, 0, stream>>>(x_in, day_w, day_b, gauss, pe_ln1_g, pe_ln1_b,
                                                day_idx, pe_v);
        launch_gemm(stream, pe_v, pe_W, pe_b, (const float*)nullptr, x_state, (bf16*)nullptr,
                    MROWS, DM, KL * NFEAT, 0);
        ln_kernel<<<MROWS, 256, 0, stream>>>(x_state, pe_ln2_g, pe_ln2_b, x_state, 1e-6f);
        for (int i = 0; i < 2; ++i) {
            ln_kernel<<<MROWS, 256, 0, stream>>>(x_state, tf_ln_g + i * DM, tf_ln_b + i * DM, hbuf, 1e-5f);
            launch_gemm(stream, hbuf, tf_qkv_W + (size_t)i * DM * 3 * DM, tf_qkv_b + i * 3 * DM,
                        (const float*)nullptr, qkvb, (bf16*)nullptr, MROWS, 3 * DM, DM, 0);
            attn_kernel<<<BSZ * NHEAD_ * SP, 256, 0, stream>>>(qkvb, rel_tab, attno);
            launch_gemm(stream, attno, tf_out_W + (size_t)i * DM * DM, tf_out_b + i * DM,
                        x_state, x_state, (bf16*)nullptr, MROWS, DM, DM, 0);
            ln_kernel<<<MROWS, 256, 0, stream>>>(x_state, tf_ffln_g + i * DM, tf_ffln_b + i * DM, hbuf, 1e-5f);
            launch_gemm(stream, hbuf, tf_fc1_W + (size_t)i * DM * FFD, tf_fc1_b + i * FFD,
                        (const float*)nullptr, (float*)nullptr, ffb, MROWS, FFD, DM, 1);
            launch_gemm(stream, ffb, tf_fc2_W + (size_t)i * FFD * DM, tf_fc2_b + i * DM,
                        x_state, x_state, (bf16*)nullptr, MROWS, DM, FFD, 0);
        }
        for (int i = 0; i < 4; ++i) {
            ln_kernel<<<MROWS, 256, 0, stream>>>(x_state, mb_norm_g + i * DM, mb_norm_b + i * DM, hbuf, 1e-5f);
            launch_gemm(stream, hbuf, mb_in_W + (size_t)i * DM * 2 * DI, mb_in_b + i * 2 * DI,
                        (const float*)nullptr, (float*)nullptr, xzb, MROWS, 2 * DI, DM, 0);
            mamba_conv_kernel<<<MROWS, 256, 0, stream>>>(xzb, mb_conv_W + (size_t)i * DI * 4,
                                                         mb_conv_b + i * DI, xcb);
            launch_gemm(stream, xcb, mb_xp_W + (size_t)i * DI * 2 * DST, mb_xp_b + i * 2 * DST,
                        (const float*)nullptr, bcb, (bf16*)nullptr, MROWS, 2 * DST, DI, 0);
            launch_gemm(stream, xcb, mb_dt_W + (size_t)i * DI * DI, mb_dt_b + i * DI,
                        (const float*)nullptr, deltab, (bf16*)nullptr, MROWS, DI, DI, 2);
            scan_kernel<<<BSZ * (DI / 16), 256, 0, stream>>>(deltab, xcb, bcb, xzb,
                                                             mb_Alog + (size_t)i * DI * DST,
                                                             mb_D + i * DI, yb);
            launch_gemm(stream, yb, mb_out_W + (size_t)i * DI * DM, mb_out_b + i * DM,
                        x_state, x_state, (bf16*)nullptr, MROWS, DM, DI, 0);
        }
        launch_gemm(stream, x_state, head_W, head_b, (const float*)nullptr, (float*)d_out, (bf16*)nullptr,
                    MROWS, NPHD, DM, 0);
    }
}

// Round 7
// 2214.546 us; speedup vs baseline: 3.0950x; 1.5103x over previous
//
#include <hip/hip_runtime.h>
#include <hip/hip_bf16.h>
#include <math.h>

typedef __hip_bfloat16 bf16;
typedef __attribute__((ext_vector_type(8))) short short8;
typedef __attribute__((ext_vector_type(4))) float floatx4;

// ---------------- constants ----------------
#define BSZ   8
#define TLEN  8192
#define NFEAT 256
#define DM    512
#define NHEAD_ 8
#define HD    64
#define SP    256          // NPATCH
#define KL    32
#define FFD   2048
#define DI    1024
#define DST   16
#define NPHD  41
#define MROWS (BSZ*SP)     // 2048

__device__ __forceinline__ float b2f(bf16 v) { return __bfloat162float(v); }
__device__ __forceinline__ short f2bs(float f) {
    union { bf16 h; short s; } u; u.h = __float2bfloat16(f); return u.s;
}
__device__ __forceinline__ float bs2f(short s) {
    union { short s; bf16 h; } u; u.s = s; return __bfloat162float(u.h);
}

__device__ __forceinline__ float ldA(const float* p, size_t i) { return p[i]; }
__device__ __forceinline__ float ldA(const bf16* p, size_t i)  { return b2f(p[i]); }
__device__ __forceinline__ float ldA(const short* p, size_t i) { return bs2f(p[i]); }
__device__ __forceinline__ void stO(float* p, size_t i, float v) { p[i] = v; }
__device__ __forceinline__ void stO(bf16* p, size_t i, float v)  { p[i] = __float2bfloat16(v); }

// load 8 consecutive elems as bf16 bit-patterns (16B aligned source for short path)
__device__ __forceinline__ short8 ld8bf(const float* p) {
    float4 v0 = *(const float4*)p;
    float4 v1 = *(const float4*)(p + 4);
    short8 r;
    r[0] = f2bs(v0.x); r[1] = f2bs(v0.y); r[2] = f2bs(v0.z); r[3] = f2bs(v0.w);
    r[4] = f2bs(v1.x); r[5] = f2bs(v1.y); r[6] = f2bs(v1.z); r[7] = f2bs(v1.w);
    return r;
}
__device__ __forceinline__ short8 ld8bf(const short* p) {
    return *(const short8*)p;
}

// ---------------- block reduce (sum of two values) over 256 threads ----------------
__device__ __forceinline__ void blk_red_sum2(float& s1, float& s2) {
    __shared__ float buf1[4], buf2[4];
    #pragma unroll
    for (int off = 32; off > 0; off >>= 1) {
        s1 += __shfl_down(s1, off, 64);
        s2 += __shfl_down(s2, off, 64);
    }
    int lane = threadIdx.x & 63, w = threadIdx.x >> 6;
    __syncthreads();
    if (lane == 0) { buf1[w] = s1; buf2[w] = s2; }
    __syncthreads();
    s1 = buf1[0] + buf1[1] + buf1[2] + buf1[3];
    s2 = buf2[0] + buf2[1] + buf2[2] + buf2[3];
}

// ---------------- weight transpose+convert: in fp32 [K][N] -> out bf16 [N][K] ----------------
__global__ void transpose_cvt(const float* __restrict__ in, short* __restrict__ out,
                              int K, int N, size_t in_ls, size_t out_ls)
{
    __shared__ float tile[32][33];
    const float* inp = in + (size_t)blockIdx.z * in_ls;
    short* outp = out + (size_t)blockIdx.z * out_ls;
    int kb = blockIdx.y * 32, nb = blockIdx.x * 32;
    int tx = threadIdx.x & 31, ty8 = threadIdx.x >> 5;
    #pragma unroll
    for (int r = 0; r < 32; r += 8)
        tile[ty8 + r][tx] = inp[(size_t)(kb + ty8 + r) * N + nb + tx];
    __syncthreads();
    #pragma unroll
    for (int r = 0; r < 32; r += 8)
        outp[(size_t)(nb + ty8 + r) * K + kb + tx] = f2bs(tile[tx][ty8 + r]);
}

// ---------------- 64x64-tile MFMA GEMM ----------------
// out = act(A[MxK] @ B + bias)(+residual). BT is bf16 [N][K]. M,N mult of 64; K mult of 32.
template<typename TA, typename TO>
__global__ __launch_bounds__(256) void mfma_gemm64(const TA* __restrict__ A,
        const short* __restrict__ BT, const float* __restrict__ bias,
        const float* __restrict__ residual, TO* __restrict__ out,
        int M, int N, int K, int act)
{
    __shared__ __align__(16) short As[64 * 40];
    __shared__ __align__(16) short Bs[64 * 40];
    int m0 = blockIdx.y * 64, n0 = blockIdx.x * 64;
    int tid = threadIdx.x;
    int w = tid >> 6, lane = tid & 63;
    int wm = (w >> 1) * 32, wn = (w & 1) * 32;
    int lm = lane & 15, quad = lane >> 4;
    floatx4 acc[2][2];
    #pragma unroll
    for (int i = 0; i < 2; ++i)
        #pragma unroll
        for (int j = 0; j < 2; ++j)
            acc[i][j] = (floatx4){0.f, 0.f, 0.f, 0.f};

    int sr = tid >> 2;          // 0..63 row
    int kq = (tid & 3) * 8;     // 0,8,16,24

    for (int kt = 0; kt < K; kt += 32) {
        short8 av = ld8bf(A + (size_t)(m0 + sr) * K + kt + kq);
        short8 bv = *(const short8*)(BT + (size_t)(n0 + sr) * K + kt + kq);
        *(short8*)&As[sr * 40 + kq] = av;
        *(short8*)&Bs[sr * 40 + kq] = bv;
        __syncthreads();
        short8 af[2], bfr[2];
        #pragma unroll
        for (int i = 0; i < 2; ++i) af[i]  = *(const short8*)&As[(wm + i * 16 + lm) * 40 + quad * 8];
        #pragma unroll
        for (int j = 0; j < 2; ++j) bfr[j] = *(const short8*)&Bs[(wn + j * 16 + lm) * 40 + quad * 8];
        #pragma unroll
        for (int i = 0; i < 2; ++i)
            #pragma unroll
            for (int j = 0; j < 2; ++j)
                acc[i][j] = __builtin_amdgcn_mfma_f32_16x16x32_bf16(af[i], bfr[j], acc[i][j], 0, 0, 0);
        __syncthreads();
    }

    #pragma unroll
    for (int i = 0; i < 2; ++i) {
        int gmb = m0 + wm + i * 16 + quad * 4;
        #pragma unroll
        for (int j = 0; j < 2; ++j) {
            int gn = n0 + wn + j * 16 + lm;
            float bia = bias[gn];
            #pragma unroll
            for (int reg = 0; reg < 4; ++reg) {
                int gm = gmb + reg;
                float v = acc[i][j][reg] + bia;
                if (act == 1)      v = 0.5f * v * (1.f + erff(v * 0.7071067811865476f));
                else if (act == 2) v = (v > 20.f) ? v : log1pf(__expf(v));
                if (residual) v += residual[(size_t)gm * N + gn];
                stO(out, (size_t)gm * N + gn, v);
            }
        }
    }
}

// ---------------- skinny GEMM (small N): out = A[MxK] @ W[KxN] + bias ----------------
template<typename TA>
__global__ __launch_bounds__(256) void skinny_gemm(const TA* __restrict__ A,
        const float* __restrict__ W, const float* __restrict__ bias,
        float* __restrict__ out, int M, int N, int K)
{
    __shared__ float As[8][68];
    int m0 = blockIdx.x * 8;
    int tid = threadIdx.x;
    int n = tid & 63, rh = tid >> 6;
    float acc0 = 0.f, acc1 = 0.f;
    for (int k0 = 0; k0 < K; k0 += 64) {
        int idx = tid * 2;
        int row = idx >> 6, kk = idx & 63;
        As[row][kk]     = ldA(A, (size_t)(m0 + row) * K + k0 + kk);
        As[row][kk + 1] = ldA(A, (size_t)(m0 + row) * K + k0 + kk + 1);
        __syncthreads();
        if (n < N) {
            for (int kk2 = 0; kk2 < 64; ++kk2) {
                float wv = W[(size_t)(k0 + kk2) * N + n];
                acc0 += As[rh][kk2] * wv;
                acc1 += As[rh + 4][kk2] * wv;
            }
        }
        __syncthreads();
    }
    if (n < N) {
        float bia = bias[n];
        out[(size_t)(m0 + rh) * N + n]     = acc0 + bia;
        out[(size_t)(m0 + rh + 4) * N + n] = acc1 + bia;
    }
}

// ---------------- stage A: day-scale + gauss conv + patch LN(8192) ----------------
__global__ void patch_kernel(const float* __restrict__ x, const float* __restrict__ dw,
                             const float* __restrict__ db, const float* __restrict__ gk,
                             const float* __restrict__ g1, const float* __restrict__ b1,
                             const int* __restrict__ day_idx, bf16* __restrict__ pe_v)
{
    __shared__ float xs[51][256];
    int blk = blockIdx.x;
    int b = blk >> 8, p = blk & 255;
    int f = threadIdx.x;
    int di = day_idx[b];
    float w  = dw[di * NFEAT + f];
    float bb = db[di * NFEAT + f];
    int t0 = p * KL - 10;
    for (int r = 0; r < 51; ++r) {
        int t = t0 + r;
        xs[r][f] = (t >= 0 && t < TLEN) ? x[((size_t)b * TLEN + t) * NFEAT + f] * w + bb : 0.f;
    }
    float gkr[20];
    #pragma unroll
    for (int k = 0; k < 20; ++k) gkr[k] = gk[f * 20 + k];
    __syncthreads();

    float c[32];
    float sum = 0.f, sumsq = 0.f;
    #pragma unroll
    for (int i = 0; i < 32; ++i) {
        float acc = 0.f;
        #pragma unroll
        for (int k = 0; k < 20; ++k) acc += xs[i + k][f] * gkr[k];
        c[i] = acc; sum += acc; sumsq += acc * acc;
    }
    blk_red_sum2(sum, sumsq);
    float mean = sum * (1.f / 8192.f);
    float var  = sumsq * (1.f / 8192.f) - mean * mean;
    float rstd = rsqrtf(fmaxf(var, 0.f) + 1e-6f);
    bf16* outp = pe_v + (size_t)blk * 8192;
    #pragma unroll
    for (int i = 0; i < 32; ++i) {
        int e = i * 256 + f;
        outp[e] = __float2bfloat16((c[i] - mean) * rstd * g1[e] + b1[e]);
    }
}

// ---------------- fallback VALU GEMM ----------------
#define BM 64
#define BN 64
#define BKK 16
template<typename TA>
__global__ void gemm_kernel(const TA* __restrict__ A, const float* __restrict__ Bw,
                            const float* __restrict__ bias, const float* __restrict__ residual,
                            float* __restrict__ outF, bf16* __restrict__ outB,
                            int M, int N, int K, int act)
{
    __shared__ float As[BKK][BM + 4];
    __shared__ float Bs[BKK][BN + 4];
    int n0 = blockIdx.x * BN, m0 = blockIdx.y * BM;
    int tid = threadIdx.x;
    int tx = tid & 15, ty = tid >> 4;
    float acc[4][4] = {};
    for (int k0 = 0; k0 < K; k0 += BKK) {
        for (int i = tid; i < BM * BKK; i += 256) {
            int m = i >> 4, k = i & 15;
            As[k][m] = ldA(A, (size_t)(m0 + m) * K + k0 + k);
        }
        for (int i = tid; i < BKK * BN; i += 256) {
            int k = i >> 6, n = i & 63;
            int gn = n0 + n;
            Bs[k][n] = (gn < N) ? Bw[(size_t)(k0 + k) * N + gn] : 0.f;
        }
        __syncthreads();
        #pragma unroll
        for (int k = 0; k < BKK; ++k) {
            float a[4], bb[4];
            #pragma unroll
            for (int i = 0; i < 4; ++i) a[i] = As[k][ty * 4 + i];
            #pragma unroll
            for (int j = 0; j < 4; ++j) bb[j] = Bs[k][tx * 4 + j];
            #pragma unroll
            for (int i = 0; i < 4; ++i)
                #pragma unroll
                for (int j = 0; j < 4; ++j) acc[i][j] += a[i] * bb[j];
        }
        __syncthreads();
    }
    #pragma unroll
    for (int i = 0; i < 4; ++i) {
        int m = m0 + ty * 4 + i;
        #pragma unroll
        for (int j = 0; j < 4; ++j) {
            int n = n0 + tx * 4 + j;
            if (n >= N) continue;
            float v = acc[i][j];
            v += bias[n];
            if (act == 1)      v = 0.5f * v * (1.f + erff(v * 0.7071067811865476f));
            else if (act == 2) v = (v > 20.f) ? v : log1pf(__expf(v));
            if (residual) v += residual[(size_t)m * N + n];
            if (outB) stO(outB, (size_t)m * N + n, v);
            else      stO(outF, (size_t)m * N + n, v);
        }
    }
}

// ---------------- LayerNorm over dim 512 ----------------
__global__ void ln_kernel(const float* __restrict__ in, const float* __restrict__ g,
                          const float* __restrict__ bta, float* __restrict__ out, float eps)
{
    int row = blockIdx.x, tid = threadIdx.x;
    const float* r = in + (size_t)row * DM;
    float v0 = r[tid], v1 = r[tid + 256];
    float s1 = v0 + v1, s2 = v0 * v0 + v1 * v1;
    blk_red_sum2(s1, s2);
    float mean = s1 * (1.f / 512.f);
    float var  = s2 * (1.f / 512.f) - mean * mean;
    float rstd = rsqrtf(fmaxf(var, 0.f) + eps);
    float* o = out + (size_t)row * DM;
    o[tid]       = (v0 - mean) * rstd * g[tid]       + bta[tid];
    o[tid + 256] = (v1 - mean) * rstd * g[tid + 256] + bta[tid + 256];
}

// ---------------- qkv permute: [row][1536] fp32 -> q/k/v [b*8+h][s][64] bf16 ----------------
__global__ void permute_qkv(const float* __restrict__ qkvb, bf16* __restrict__ qh,
                            bf16* __restrict__ kh, bf16* __restrict__ vh)
{
    int r = blockIdx.x;          // b*256+s
    int b = r >> 8, s = r & 255;
    for (int c = threadIdx.x; c < 1536; c += 256) {
        int type = c >> 9;
        int inner = c & 511;
        int h = inner >> 6, d = inner & 63;
        bf16 v = __float2bfloat16(qkvb[(size_t)r * 1536 + c]);
        bf16* dst = (type == 0) ? qh : (type == 1 ? kh : vh);
        dst[((size_t)(b * 8 + h) * 256 + s) * 64 + d] = v;
    }
}

// ---------------- attention v3: registers-only softmax, head-major bf16 QKV ----------------
// grid: (b,h,qc) = 8*8*8 = 512 blocks; 256 threads; 32 q-rows per block.
__global__ __launch_bounds__(256, 4) void attn_kernel3(const bf16* __restrict__ qh,
        const bf16* __restrict__ kh, const bf16* __restrict__ vh,
        const float* __restrict__ rel_table, float* __restrict__ attno)
{
    __shared__ __align__(16) float Qs[32][68];
    __shared__ __align__(16) float KVs[64][68];
    __shared__ bf16 Ps[32][264];
    int blk = blockIdx.x;
    int qc = blk & 7; int bh = blk >> 3; int h = bh & 7; int b = bh >> 3;
    int q0 = qc * 32;
    int tid = threadIdx.x;
    const bf16* qb = qh + (size_t)bh * 256 * 64;
    const bf16* kb = kh + (size_t)bh * 256 * 64;
    const bf16* vb = vh + (size_t)bh * 256 * 64;

    // stage Q tile: 32 rows x 8 groups of 8
    {
        int row = tid >> 3, grp = tid & 7;
        short8 v = *(const short8*)((const short*)qb + (size_t)(q0 + row) * 64 + grp * 8);
        float4 f0 = {bs2f(v[0]), bs2f(v[1]), bs2f(v[2]), bs2f(v[3])};
        float4 f1 = {bs2f(v[4]), bs2f(v[5]), bs2f(v[6]), bs2f(v[7])};
        *(float4*)&Qs[row][grp * 8]     = f0;
        *(float4*)&Qs[row][grp * 8 + 4] = f1;
    }

    int tq = tid >> 3, kl = tid & 7;
    int gq = q0 + tq;
    float sc[4][8];
    float mx = -3e38f;

    // phase 1: scores (kept in registers)
    #pragma unroll
    for (int kc = 0; kc < 4; ++kc) {
        __syncthreads();
        #pragma unroll
        for (int idx = 0; idx < 2; ++idx) {
            int ii = tid + idx * 256;
            int row = ii >> 3, grp = ii & 7;
            short8 v = *(const short8*)((const short*)kb + (size_t)(kc * 64 + row) * 64 + grp * 8);
            float4 f0 = {bs2f(v[0]), bs2f(v[1]), bs2f(v[2]), bs2f(v[3])};
            float4 f1 = {bs2f(v[4]), bs2f(v[5]), bs2f(v[6]), bs2f(v[7])};
            *(float4*)&KVs[row][grp * 8]     = f0;
            *(float4*)&KVs[row][grp * 8 + 4] = f1;
        }
        __syncthreads();
        float s8[8] = {0.f, 0.f, 0.f, 0.f, 0.f, 0.f, 0.f, 0.f};
        for (int d0 = 0; d0 < 64; d0 += 16) {
            float4 qv0 = *(const float4*)&Qs[tq][d0];
            float4 qv1 = *(const float4*)&Qs[tq][d0 + 4];
            float4 qv2 = *(const float4*)&Qs[tq][d0 + 8];
            float4 qv3 = *(const float4*)&Qs[tq][d0 + 12];
            #pragma unroll
            for (int j = 0; j < 8; ++j) {
                int kk = kl * 8 + j;
                float4 k0 = *(const float4*)&KVs[kk][d0];
                float4 k1 = *(const float4*)&KVs[kk][d0 + 4];
                float4 k2 = *(const float4*)&KVs[kk][d0 + 8];
                float4 k3 = *(const float4*)&KVs[kk][d0 + 12];
                s8[j] += qv0.x * k0.x + qv0.y * k0.y + qv0.z * k0.z + qv0.w * k0.w
                       + qv1.x * k1.x + qv1.y * k1.y + qv1.z * k1.z + qv1.w * k1.w
                       + qv2.x * k2.x + qv2.y * k2.y + qv2.z * k2.z + qv2.w * k2.w
                       + qv3.x * k3.x + qv3.y * k3.y + qv3.z * k3.z + qv3.w * k3.w;
            }
        }
        #pragma unroll
        for (int j = 0; j < 8; ++j) {
            int gk = kc * 64 + kl * 8 + j;
            float s = s8[j] * 0.125f;
            int rel = gk - gq; rel = rel < -128 ? -128 : (rel > 128 ? 128 : rel);
            s += rel_table[h * 257 + rel + 128];
            if (gk > gq) s -= 1e9f;
            sc[kc][j] = s;
            mx = fmaxf(mx, s);
        }
    }
    // row max over the 8-lane group
    mx = fmaxf(mx, __shfl_xor(mx, 1, 64));
    mx = fmaxf(mx, __shfl_xor(mx, 2, 64));
    mx = fmaxf(mx, __shfl_xor(mx, 4, 64));
    // exp + sum, write P (bf16) to LDS
    float lsum = 0.f;
    #pragma unroll
    for (int kc = 0; kc < 4; ++kc)
        #pragma unroll
        for (int j = 0; j < 8; ++j) {
            float e = __expf(sc[kc][j] - mx);
            lsum += e;
            Ps[tq][kc * 64 + kl * 8 + j] = __float2bfloat16(e);
        }
    lsum += __shfl_xor(lsum, 1, 64);
    lsum += __shfl_xor(lsum, 2, 64);
    lsum += __shfl_xor(lsum, 4, 64);
    float inv = 1.f / lsum;

    // phase 2: P @ V — thread owns dims kl*8..kl*8+7 of row tq
    float o[8] = {0.f, 0.f, 0.f, 0.f, 0.f, 0.f, 0.f, 0.f};
    #pragma unroll
    for (int kc = 0; kc < 4; ++kc) {
        __syncthreads();
        #pragma unroll
        for (int idx = 0; idx < 2; ++idx) {
            int ii = tid + idx * 256;
            int row = ii >> 3, grp = ii & 7;
            short8 v = *(const short8*)((const short*)vb + (size_t)(kc * 64 + row) * 64 + grp * 8);
            float4 f0 = {bs2f(v[0]), bs2f(v[1]), bs2f(v[2]), bs2f(v[3])};
            float4 f1 = {bs2f(v[4]), bs2f(v[5]), bs2f(v[6]), bs2f(v[7])};
            *(float4*)&KVs[row][grp * 8]     = f0;
            *(float4*)&KVs[row][grp * 8 + 4] = f1;
        }
        __syncthreads();
        for (int kk = 0; kk < 64; ++kk) {
            float p = b2f(Ps[tq][kc * 64 + kk]);
            float4 v0 = *(const float4*)&KVs[kk][kl * 8];
            float4 v1 = *(const float4*)&KVs[kk][kl * 8 + 4];
            o[0] += p * v0.x; o[1] += p * v0.y; o[2] += p * v0.z; o[3] += p * v0.w;
            o[4] += p * v1.x; o[5] += p * v1.y; o[6] += p * v1.z; o[7] += p * v1.w;
        }
    }
    float* op = attno + (size_t)(b * 256 + gq) * DM + h * 64 + kl * 8;
    #pragma unroll
    for (int dj = 0; dj < 8; ++dj) op[dj] = o[dj] * inv;
}

// ---------------- old attention (fallback path) ----------------
__global__ void attn_kernel(const float* __restrict__ qkv, const float* __restrict__ rel_table,
                            float* __restrict__ attno)
{
    __shared__ float qv[64];
    __shared__ float sc[256];
    __shared__ float rb[256];
    __shared__ float op[4][64];
    int blk = blockIdx.x;
    int q = blk & 255, bh = blk >> 8;
    int hh = bh & 7, b = bh >> 3;
    int tid = threadIdx.x;
    const float* base = qkv + (size_t)b * 256 * 1536;
    if (tid < 64) qv[tid] = base[(size_t)q * 1536 + hh * 64 + tid];
    __syncthreads();
    const float* krow = base + (size_t)tid * 1536 + 512 + hh * 64;
    float d = 0.f;
    #pragma unroll 16
    for (int i = 0; i < 64; ++i) d += qv[i] * krow[i];
    float s = d * 0.125f;
    int rel = tid - q; rel = rel < -128 ? -128 : (rel > 128 ? 128 : rel);
    s += rel_table[hh * 257 + rel + 128];
    if (tid > q) s += -1e9f;
    sc[tid] = s; rb[tid] = s;
    __syncthreads();
    for (int st = 128; st > 0; st >>= 1) { if (tid < st) rb[tid] = fmaxf(rb[tid], rb[tid + st]); __syncthreads(); }
    float mx = rb[0];
    __syncthreads();
    float e = __expf(s - mx);
    sc[tid] = e; rb[tid] = e;
    __syncthreads();
    for (int st = 128; st > 0; st >>= 1) { if (tid < st) rb[tid] += rb[tid + st]; __syncthreads(); }
    float inv = 1.f / rb[0];
    __syncthreads();
    int dd = tid & 63, c = tid >> 6;
    const float* vbase = base + 1024 + hh * 64 + dd;
    float o = 0.f;
    for (int k = c * 64; k < c * 64 + 64; ++k) o += sc[k] * vbase[(size_t)k * 1536];
    op[c][dd] = o;
    __syncthreads();
    if (tid < 64) {
        float r = (op[0][tid] + op[1][tid] + op[2][tid] + op[3][tid]) * inv;
        attno[((size_t)(b * 256 + q)) * DM + hh * 64 + tid] = r;
    }
}

// ---------------- mamba depthwise conv (k=4 causal) + silu ----------------
__global__ void mamba_conv_kernel(const bf16* __restrict__ xz, const float* __restrict__ cW,
                                  const float* __restrict__ cb, bf16* __restrict__ xc)
{
    int row = blockIdx.x;
    int b = row >> 8, t = row & 255;
    int tid = threadIdx.x;
    #pragma unroll
    for (int j = 0; j < 4; ++j) {
        int dd = tid + j * 256;
        float acc = cb[dd];
        #pragma unroll
        for (int k = 0; k < 4; ++k) {
            int ts = t - 3 + k;
            if (ts >= 0) acc += b2f(xz[((size_t)(b * 256 + ts)) * 2048 + dd]) * cW[dd * 4 + k];
        }
        xc[(size_t)row * DI + dd] = __float2bfloat16(acc * (1.f / (1.f + __expf(-acc))));
    }
}

// ---------------- selective scan ----------------
__global__ void scan_kernel(const float* __restrict__ delta, const bf16* __restrict__ xcv,
                            const float* __restrict__ bc, const bf16* __restrict__ xz,
                            const float* __restrict__ Alog, const float* __restrict__ Dp,
                            float* __restrict__ y)
{
    int blk = blockIdx.x;
    int b = blk >> 6, chunk = blk & 63;
    int tid = threadIdx.x;
    int s = tid & 15, dl = tid >> 4;
    int d = chunk * 16 + dl;
    float A  = -__expf(Alog[d * DST + s]);
    float Dv = Dp[d];
    float h = 0.f;
    for (int t = 0; t < 256; ++t) {
        size_t r = (size_t)(b * 256 + t);
        float dt = delta[r * DI + d];
        float u  = b2f(xcv[r * DI + d]);
        float Bv = bc[r * 32 + s];
        float Cv = bc[r * 32 + 16 + s];
        h = __expf(dt * A) * h + dt * Bv * u;
        float contrib = h * Cv;
        contrib += __shfl_xor(contrib, 1, 64);
        contrib += __shfl_xor(contrib, 2, 64);
        contrib += __shfl_xor(contrib, 4, 64);
        contrib += __shfl_xor(contrib, 8, 64);
        if (s == 0) {
            float z = b2f(xz[r * 2048 + DI + d]);
            y[r * DI + d] = (contrib + u * Dv) * (z * (1.f / (1.f + __expf(-z))));
        }
    }
}

// ---------------- host helpers ----------------
template<typename TA>
static inline void launch_gemm(hipStream_t st, const TA* A, const float* Bw, const float* bias,
                               const float* res, float* outF, bf16* outB, int M, int N, int K, int act)
{
    dim3 grid((N + BN - 1) / BN, M / BM);
    gemm_kernel<TA><<<grid, 256, 0, st>>>(A, Bw, bias, res, outF, outB, M, N, K, act);
}

template<typename TA, typename TO>
static inline void launch_mfma(hipStream_t st, const TA* A, const short* BT, const float* bias,
                               const float* res, TO* out, int M, int N, int K, int act)
{
    dim3 grid(N / 64, M / 64);
    mfma_gemm64<TA, TO><<<grid, 256, 0, st>>>(A, BT, bias, res, out, M, N, K, act);
}

static inline void launch_transpose(hipStream_t st, const float* in, short* out,
                                    int K, int N, int layers, size_t in_ls, size_t out_ls)
{
    dim3 grid(N / 32, K / 32, layers);
    transpose_cvt<<<grid, 256, 0, st>>>(in, out, K, N, in_ls, out_ls);
}

extern "C" void kernel_launch(void* const* d_in, const int* in_sizes, int n_in,
                              void* d_out, int out_size, void* d_ws, size_t ws_size,
                              hipStream_t stream)
{
    const float* x_in     = (const float*)d_in[0];
    const float* day_w    = (const float*)d_in[1];
    const float* day_b    = (const float*)d_in[2];
    const float* gauss    = (const float*)d_in[3];
    const float* pe_ln1_g = (const float*)d_in[4];
    const float* pe_ln1_b = (const float*)d_in[5];
    const float* pe_W     = (const float*)d_in[6];
    const float* pe_b     = (const float*)d_in[7];
    const float* pe_ln2_g = (const float*)d_in[8];
    const float* pe_ln2_b = (const float*)d_in[9];
    const float* rel_tab  = (const float*)d_in[10];
    const float* tf_ln_g  = (const float*)d_in[11];
    const float* tf_ln_b  = (const float*)d_in[12];
    const float* tf_qkv_W = (const float*)d_in[13];
    const float* tf_qkv_b = (const float*)d_in[14];
    const float* tf_out_W = (const float*)d_in[15];
    const float* tf_out_b = (const float*)d_in[16];
    const float* tf_ffln_g= (const float*)d_in[17];
    const float* tf_ffln_b= (const float*)d_in[18];
    const float* tf_fc1_W = (const float*)d_in[19];
    const float* tf_fc1_b = (const float*)d_in[20];
    const float* tf_fc2_W = (const float*)d_in[21];
    const float* tf_fc2_b = (const float*)d_in[22];
    const float* mb_norm_g= (const float*)d_in[23];
    const float* mb_norm_b= (const float*)d_in[24];
    const float* mb_in_W  = (const float*)d_in[25];
    const float* mb_in_b  = (const float*)d_in[26];
    const float* mb_conv_W= (const float*)d_in[27];
    const float* mb_conv_b= (const float*)d_in[28];
    const float* mb_xp_W  = (const float*)d_in[29];
    const float* mb_xp_b  = (const float*)d_in[30];
    const float* mb_dt_W  = (const float*)d_in[31];
    const float* mb_dt_b  = (const float*)d_in[32];
    const float* mb_Alog  = (const float*)d_in[33];
    const float* mb_D     = (const float*)d_in[34];
    const float* mb_out_W = (const float*)d_in[35];
    const float* mb_out_b = (const float*)d_in[36];
    const float* head_W   = (const float*)d_in[37];
    const float* head_b   = (const float*)d_in[38];
    const int*   day_idx  = (const int*)d_in[39];

    bool big = ws_size >= ((size_t)59 << 20);

    if (big) {
        char* base = (char*)d_ws;
        short* wT = (short*)base;
        float* x_state = (float*)(base + ((size_t)22 << 20));
        char* arena = base + ((size_t)26 << 20);

        bf16*  pe_v  = (bf16*)arena;                           // 32 MB
        float* hbuf  = (float*)arena;                          // 4 MB
        float* qkvb  = (float*)(arena + ((size_t)4  << 20));   // 12 MB
        float* attno = (float*)(arena + ((size_t)16 << 20));   // 4 MB
        bf16*  ffb   = (bf16*) (arena + ((size_t)20 << 20));   // 8 MB (lifetime disjoint w/ qh/kh/vh)
        bf16*  qh    = (bf16*) (arena + ((size_t)20 << 20));   // 2 MB
        bf16*  kh    = (bf16*) (arena + ((size_t)22 << 20));   // 2 MB
        bf16*  vh    = (bf16*) (arena + ((size_t)24 << 20));   // 2 MB
        bf16*  xzb   = (bf16*) (arena + ((size_t)4  << 20));   // 8 MB
        bf16*  xcb   = (bf16*) (arena + ((size_t)12 << 20));   // 4 MB
        float* deltab= (float*)(arena + ((size_t)16 << 20));   // 8 MB
        float* yb    = (float*)(arena + ((size_t)24 << 20));   // 8 MB
        float* bcb   = (float*)(arena + ((size_t)32 << 20));   // 0.25 MB

        const size_t qkvT_o = 0,            qkvT_ls = (size_t)1536 * 512;
        const size_t outT_o = 1572864,      outT_ls = (size_t)512 * 512;
        const size_t fc1T_o = 2097152,      fc1T_ls = (size_t)2048 * 512;
        const size_t fc2T_o = 4194304,      fc2T_ls = (size_t)512 * 2048;
        const size_t inT_o  = 0,            inT_ls  = (size_t)2048 * 512;
        const size_t dtT_o  = 4194304,      dtT_ls  = (size_t)1024 * 1024;
        const size_t owT_o  = 8388608,      owT_ls  = (size_t)512 * 1024;

        // ---- stage A ----
        launch_transpose(stream, pe_W, wT, 8192, 512, 1, 0, 0);
        patch_kernel<<<MROWS, 256, 0, stream>>>(x_in, day_w, day_b, gauss, pe_ln1_g, pe_ln1_b,
                                                day_idx, pe_v);
        launch_mfma(stream, (const short*)pe_v, wT, pe_b, (const float*)nullptr, x_state,
                    MROWS, DM, KL * NFEAT, 0);
        ln_kernel<<<MROWS, 256, 0, stream>>>(x_state, pe_ln2_g, pe_ln2_b, x_state, 1e-6f);

        // ---- transformer weights ----
        launch_transpose(stream, tf_qkv_W, wT + qkvT_o, 512, 1536, 2, (size_t)512 * 1536, qkvT_ls);
        launch_transpose(stream, tf_out_W, wT + outT_o, 512, 512, 2, (size_t)512 * 512, outT_ls);
        launch_transpose(stream, tf_fc1_W, wT + fc1T_o, 512, 2048, 2, (size_t)512 * 2048, fc1T_ls);
        launch_transpose(stream, tf_fc2_W, wT + fc2T_o, 2048, 512, 2, (size_t)2048 * 512, fc2T_ls);

        for (int i = 0; i < 2; ++i) {
            ln_kernel<<<MROWS, 256, 0, stream>>>(x_state, tf_ln_g + i * DM, tf_ln_b + i * DM, hbuf, 1e-5f);
            launch_mfma(stream, hbuf, wT + qkvT_o + i * qkvT_ls, tf_qkv_b + i * 3 * DM,
                        (const float*)nullptr, qkvb, MROWS, 3 * DM, DM, 0);
            permute_qkv<<<MROWS, 256, 0, stream>>>(qkvb, qh, kh, vh);
            attn_kernel3<<<BSZ * NHEAD_ * 8, 256, 0, stream>>>(qh, kh, vh, rel_tab, attno);
            launch_mfma(stream, attno, wT + outT_o + i * outT_ls, tf_out_b + i * DM,
                        x_state, x_state, MROWS, DM, DM, 0);
            ln_kernel<<<MROWS, 256, 0, stream>>>(x_state, tf_ffln_g + i * DM, tf_ffln_b + i * DM, hbuf, 1e-5f);
            launch_mfma(stream, hbuf, wT + fc1T_o + i * fc1T_ls, tf_fc1_b + i * FFD,
                        (const float*)nullptr, ffb, MROWS, FFD, DM, 1);
            launch_mfma(stream, (const short*)ffb, wT + fc2T_o + i * fc2T_ls, tf_fc2_b + i * DM,
                        x_state, x_state, MROWS, DM, FFD, 0);
        }

        // ---- mamba weights ----
        launch_transpose(stream, mb_in_W, wT + inT_o, 512, 2048, 4, (size_t)512 * 2048, inT_ls);
        launch_transpose(stream, mb_dt_W, wT + dtT_o, 1024, 1024, 4, (size_t)1024 * 1024, dtT_ls);
        launch_transpose(stream, mb_out_W, wT + owT_o, 1024, 512, 4, (size_t)1024 * 512, owT_ls);

        for (int i = 0; i < 4; ++i) {
            ln_kernel<<<MROWS, 256, 0, stream>>>(x_state, mb_norm_g + i * DM, mb_norm_b + i * DM, hbuf, 1e-5f);
            launch_mfma(stream, hbuf, wT + inT_o + i * inT_ls, mb_in_b + i * 2 * DI,
                        (const float*)nullptr, xzb, MROWS, 2 * DI, DM, 0);
            mamba_conv_kernel<<<MROWS, 256, 0, stream>>>(xzb, mb_conv_W + (size_t)i * DI * 4,
                                                         mb_conv_b + i * DI, xcb);
            skinny_gemm<<<MROWS / 8, 256, 0, stream>>>((const short*)xcb,
                        mb_xp_W + (size_t)i * DI * 2 * DST, mb_xp_b + i * 2 * DST,
                        bcb, MROWS, 2 * DST, DI);
            launch_mfma(stream, (const short*)xcb, wT + dtT_o + i * dtT_ls, mb_dt_b + i * DI,
                        (const float*)nullptr, deltab, MROWS, DI, DI, 2);
            scan_kernel<<<BSZ * (DI / 16), 256, 0, stream>>>(deltab, xcb, bcb, xzb,
                                                             mb_Alog + (size_t)i * DI * DST,
                                                             mb_D + i * DI, yb);
            launch_mfma(stream, yb, wT + owT_o + i * owT_ls, mb_out_b + i * DM,
                        x_state, x_state, MROWS, DM, DI, 0);
        }

        skinny_gemm<<<MROWS / 8, 256, 0, stream>>>(x_state, head_W, head_b,
                    (float*)d_out, MROWS, NPHD, DM);
    } else {
        // ---- fallback: all-VALU path ----
        char* base = (char*)d_ws;
        float* x_state = (float*)base;
        char* arena = base + ((size_t)4 << 20);
        bf16* pe_v = (bf16*)arena;
        float* hbuf  = (float*)arena;
        float* qkvb  = (float*)(arena + ((size_t)4  << 20));
        float* attno = (float*)(arena + ((size_t)16 << 20));
        bf16*  ffb   = (bf16*) (arena + ((size_t)20 << 20));
        bf16*  xzb   = (bf16*) (arena + ((size_t)4  << 20));
        bf16*  xcb   = (bf16*) (arena + ((size_t)12 << 20));
        float* deltab= (float*)(arena + ((size_t)16 << 20));
        float* yb    = (float*)(arena + ((size_t)24 << 20));
        float* bcb   = (float*)(arena + ((size_t)32 << 20));

        patch_kernel<<<MROWS, 256, 0, stream>>>(x_in, day_w, day_b, gauss, pe_ln1_g, pe_ln1_b,
                                                day_idx, pe_v);
        launch_gemm(stream, pe_v, pe_W, pe_b, (const float*)nullptr, x_state, (bf16*)nullptr,
                    MROWS, DM, KL * NFEAT, 0);
        ln_kernel<<<MROWS, 256, 0, stream>>>(x_state, pe_ln2_g, pe_ln2_b, x_state, 1e-6f);
        for (int i = 0; i < 2; ++i) {
            ln_kernel<<<MROWS, 256, 0, stream>>>(x_state, tf_ln_g + i * DM, tf_ln_b + i * DM, hbuf, 1e-5f);
            launch_gemm(stream, hbuf, tf_qkv_W + (size_t)i * DM * 3 * DM, tf_qkv_b + i * 3 * DM,
                        (const float*)nullptr, qkvb, (bf16*)nullptr, MROWS, 3 * DM, DM, 0);
            attn_kernel<<<BSZ * NHEAD_ * SP, 256, 0, stream>>>(qkvb, rel_tab, attno);
            launch_gemm(stream, attno, tf_out_W + (size_t)i * DM * DM, tf_out_b + i * DM,
                        x_state, x_state, (bf16*)nullptr, MROWS, DM, DM, 0);
            ln_kernel<<<MROWS, 256, 0, stream>>>(x_state, tf_ffln_g + i * DM, tf_ffln_b + i * DM, hbuf, 1e-5f);
            launch_gemm(stream, hbuf, tf_fc1_W + (size_t)i * DM * FFD, tf_fc1_b + i * FFD,
                        (const float*)nullptr, (float*)nullptr, ffb, MROWS, FFD, DM, 1);
            launch_gemm(stream, ffb, tf_fc2_W + (size_t)i * FFD * DM, tf_fc2_b + i * DM,
                        x_state, x_state, (bf16*)nullptr, MROWS, DM, FFD, 0);
        }
        for (int i = 0; i < 4; ++i) {
            ln_kernel<<<MROWS, 256, 0, stream>>>(x_state, mb_norm_g + i * DM, mb_norm_b + i * DM, hbuf, 1e-5f);
            launch_gemm(stream, hbuf, mb_in_W + (size_t)i * DM * 2 * DI, mb_in_b + i * 2 * DI,
                        (const float*)nullptr, (float*)nullptr, xzb, MROWS, 2 * DI, DM, 0);
            mamba_conv_kernel<<<MROWS, 256, 0, stream>>>(xzb, mb_conv_W + (size_t)i * DI * 4,
                                                         mb_conv_b + i * DI, xcb);
            launch_gemm(stream, xcb, mb_xp_W + (size_t)i * DI * 2 * DST, mb_xp_b + i * 2 * DST,
                        (const float*)nullptr, bcb, (bf16*)nullptr, MROWS, 2 * DST, DI, 0);
            launch_gemm(stream, xcb, mb_dt_W + (size_t)i * DI * DI, mb_dt_b + i * DI,
                        (const float*)nullptr, deltab, (bf16*)nullptr, MROWS, DI, DI, 2);
            scan_kernel<<<BSZ * (DI / 16), 256, 0, stream>>>(deltab, xcb, bcb, xzb,
                                                             mb_Alog + (size_t)i * DI * DST,
                                                             mb_D + i * DI, yb);
            launch_gemm(stream, yb, mb_out_W + (size_t)i * DI * DM, mb_out_b + i * DM,
                        x_state, x_state, (bf16*)nullptr, MROWS, DM, DI, 0);
        }
        launch_gemm(stream, x_state, head_W, head_b, (const float*)nullptr, (float*)d_out, (bf16*)nullptr,
                    MROWS, NPHD, DM, 0);
    }
}

// Round 8
// 1677.765 us; speedup vs baseline: 4.0852x; 1.3199x over previous
//
#include <hip/hip_runtime.h>
#include <hip/hip_bf16.h>
#include <math.h>

typedef __hip_bfloat16 bf16;
typedef __attribute__((ext_vector_type(8))) short short8;
typedef __attribute__((ext_vector_type(4))) float floatx4;

// ---------------- constants ----------------
#define BSZ   8
#define TLEN  8192
#define NFEAT 256
#define DM    512
#define NHEAD_ 8
#define HD    64
#define SP    256          // NPATCH
#define KL    32
#define FFD   2048
#define DI    1024
#define DST   16
#define NPHD  41
#define MROWS (BSZ*SP)     // 2048

__device__ __forceinline__ float b2f(bf16 v) { return __bfloat162float(v); }
__device__ __forceinline__ short f2bs(float f) {
    union { bf16 h; short s; } u; u.h = __float2bfloat16(f); return u.s;
}
__device__ __forceinline__ float bs2f(short s) {
    union { short s; bf16 h; } u; u.s = s; return __bfloat162float(u.h);
}

__device__ __forceinline__ float ldA(const float* p, size_t i) { return p[i]; }
__device__ __forceinline__ float ldA(const bf16* p, size_t i)  { return b2f(p[i]); }
__device__ __forceinline__ float ldA(const short* p, size_t i) { return bs2f(p[i]); }
__device__ __forceinline__ void stO(float* p, size_t i, float v) { p[i] = v; }
__device__ __forceinline__ void stO(bf16* p, size_t i, float v)  { p[i] = __float2bfloat16(v); }

// load 8 consecutive elems as bf16 bit-patterns (16B aligned source for short path)
__device__ __forceinline__ short8 ld8bf(const float* p) {
    float4 v0 = *(const float4*)p;
    float4 v1 = *(const float4*)(p + 4);
    short8 r;
    r[0] = f2bs(v0.x); r[1] = f2bs(v0.y); r[2] = f2bs(v0.z); r[3] = f2bs(v0.w);
    r[4] = f2bs(v1.x); r[5] = f2bs(v1.y); r[6] = f2bs(v1.z); r[7] = f2bs(v1.w);
    return r;
}
__device__ __forceinline__ short8 ld8bf(const short* p) {
    return *(const short8*)p;
}

// ---------------- block reduce (sum of two values) over 256 threads ----------------
__device__ __forceinline__ void blk_red_sum2(float& s1, float& s2) {
    __shared__ float buf1[4], buf2[4];
    #pragma unroll
    for (int off = 32; off > 0; off >>= 1) {
        s1 += __shfl_down(s1, off, 64);
        s2 += __shfl_down(s2, off, 64);
    }
    int lane = threadIdx.x & 63, w = threadIdx.x >> 6;
    __syncthreads();
    if (lane == 0) { buf1[w] = s1; buf2[w] = s2; }
    __syncthreads();
    s1 = buf1[0] + buf1[1] + buf1[2] + buf1[3];
    s2 = buf2[0] + buf2[1] + buf2[2] + buf2[3];
}

// ---------------- weight transpose+convert: in fp32 [K][N] -> out bf16 [N][K] ----------------
__global__ void transpose_cvt(const float* __restrict__ in, short* __restrict__ out,
                              int K, int N, size_t in_ls, size_t out_ls)
{
    __shared__ float tile[32][33];
    const float* inp = in + (size_t)blockIdx.z * in_ls;
    short* outp = out + (size_t)blockIdx.z * out_ls;
    int kb = blockIdx.y * 32, nb = blockIdx.x * 32;
    int tx = threadIdx.x & 31, ty8 = threadIdx.x >> 5;
    #pragma unroll
    for (int r = 0; r < 32; r += 8)
        tile[ty8 + r][tx] = inp[(size_t)(kb + ty8 + r) * N + nb + tx];
    __syncthreads();
    #pragma unroll
    for (int r = 0; r < 32; r += 8)
        outp[(size_t)(nb + ty8 + r) * K + kb + tx] = f2bs(tile[tx][ty8 + r]);
}

// ---------------- 64x64-tile MFMA GEMM ----------------
// out = act(A[MxK] @ B + bias)(+residual). BT is bf16 [N][K]. M,N mult of 64; K mult of 32.
template<typename TA, typename TO>
__global__ __launch_bounds__(256) void mfma_gemm64(const TA* __restrict__ A,
        const short* __restrict__ BT, const float* __restrict__ bias,
        const float* __restrict__ residual, TO* __restrict__ out,
        int M, int N, int K, int act)
{
    __shared__ __align__(16) short As[64 * 40];
    __shared__ __align__(16) short Bs[64 * 40];
    int m0 = blockIdx.y * 64, n0 = blockIdx.x * 64;
    int tid = threadIdx.x;
    int w = tid >> 6, lane = tid & 63;
    int wm = (w >> 1) * 32, wn = (w & 1) * 32;
    int lm = lane & 15, quad = lane >> 4;
    floatx4 acc[2][2];
    #pragma unroll
    for (int i = 0; i < 2; ++i)
        #pragma unroll
        for (int j = 0; j < 2; ++j)
            acc[i][j] = (floatx4){0.f, 0.f, 0.f, 0.f};

    int sr = tid >> 2;          // 0..63 row
    int kq = (tid & 3) * 8;     // 0,8,16,24

    for (int kt = 0; kt < K; kt += 32) {
        short8 av = ld8bf(A + (size_t)(m0 + sr) * K + kt + kq);
        short8 bv = *(const short8*)(BT + (size_t)(n0 + sr) * K + kt + kq);
        *(short8*)&As[sr * 40 + kq] = av;
        *(short8*)&Bs[sr * 40 + kq] = bv;
        __syncthreads();
        short8 af[2], bfr[2];
        #pragma unroll
        for (int i = 0; i < 2; ++i) af[i]  = *(const short8*)&As[(wm + i * 16 + lm) * 40 + quad * 8];
        #pragma unroll
        for (int j = 0; j < 2; ++j) bfr[j] = *(const short8*)&Bs[(wn + j * 16 + lm) * 40 + quad * 8];
        #pragma unroll
        for (int i = 0; i < 2; ++i)
            #pragma unroll
            for (int j = 0; j < 2; ++j)
                acc[i][j] = __builtin_amdgcn_mfma_f32_16x16x32_bf16(af[i], bfr[j], acc[i][j], 0, 0, 0);
        __syncthreads();
    }

    #pragma unroll
    for (int i = 0; i < 2; ++i) {
        int gmb = m0 + wm + i * 16 + quad * 4;
        #pragma unroll
        for (int j = 0; j < 2; ++j) {
            int gn = n0 + wn + j * 16 + lm;
            float bia = bias[gn];
            #pragma unroll
            for (int reg = 0; reg < 4; ++reg) {
                int gm = gmb + reg;
                float v = acc[i][j][reg] + bia;
                if (act == 1)      v = 0.5f * v * (1.f + erff(v * 0.7071067811865476f));
                else if (act == 2) v = (v > 20.f) ? v : log1pf(__expf(v));
                if (residual) v += residual[(size_t)gm * N + gn];
                stO(out, (size_t)gm * N + gn, v);
            }
        }
    }
}

// ---------------- skinny GEMM (small N): out = A[MxK] @ W[KxN] + bias ----------------
template<typename TA>
__global__ __launch_bounds__(256) void skinny_gemm(const TA* __restrict__ A,
        const float* __restrict__ W, const float* __restrict__ bias,
        float* __restrict__ out, int M, int N, int K)
{
    __shared__ float As[8][68];
    int m0 = blockIdx.x * 8;
    int tid = threadIdx.x;
    int n = tid & 63, rh = tid >> 6;
    float acc0 = 0.f, acc1 = 0.f;
    for (int k0 = 0; k0 < K; k0 += 64) {
        int idx = tid * 2;
        int row = idx >> 6, kk = idx & 63;
        As[row][kk]     = ldA(A, (size_t)(m0 + row) * K + k0 + kk);
        As[row][kk + 1] = ldA(A, (size_t)(m0 + row) * K + k0 + kk + 1);
        __syncthreads();
        if (n < N) {
            for (int kk2 = 0; kk2 < 64; ++kk2) {
                float wv = W[(size_t)(k0 + kk2) * N + n];
                acc0 += As[rh][kk2] * wv;
                acc1 += As[rh + 4][kk2] * wv;
            }
        }
        __syncthreads();
    }
    if (n < N) {
        float bia = bias[n];
        out[(size_t)(m0 + rh) * N + n]     = acc0 + bia;
        out[(size_t)(m0 + rh + 4) * N + n] = acc1 + bia;
    }
}

// ---------------- stage A: day-scale + gauss conv + patch LN(8192) ----------------
__global__ void patch_kernel(const float* __restrict__ x, const float* __restrict__ dw,
                             const float* __restrict__ db, const float* __restrict__ gk,
                             const float* __restrict__ g1, const float* __restrict__ b1,
                             const int* __restrict__ day_idx, bf16* __restrict__ pe_v)
{
    __shared__ float xs[51][256];
    int blk = blockIdx.x;
    int b = blk >> 8, p = blk & 255;
    int f = threadIdx.x;
    int di = day_idx[b];
    float w  = dw[di * NFEAT + f];
    float bb = db[di * NFEAT + f];
    int t0 = p * KL - 10;
    for (int r = 0; r < 51; ++r) {
        int t = t0 + r;
        xs[r][f] = (t >= 0 && t < TLEN) ? x[((size_t)b * TLEN + t) * NFEAT + f] * w + bb : 0.f;
    }
    float gkr[20];
    #pragma unroll
    for (int k = 0; k < 20; ++k) gkr[k] = gk[f * 20 + k];
    __syncthreads();

    float c[32];
    float sum = 0.f, sumsq = 0.f;
    #pragma unroll
    for (int i = 0; i < 32; ++i) {
        float acc = 0.f;
        #pragma unroll
        for (int k = 0; k < 20; ++k) acc += xs[i + k][f] * gkr[k];
        c[i] = acc; sum += acc; sumsq += acc * acc;
    }
    blk_red_sum2(sum, sumsq);
    float mean = sum * (1.f / 8192.f);
    float var  = sumsq * (1.f / 8192.f) - mean * mean;
    float rstd = rsqrtf(fmaxf(var, 0.f) + 1e-6f);
    bf16* outp = pe_v + (size_t)blk * 8192;
    #pragma unroll
    for (int i = 0; i < 32; ++i) {
        int e = i * 256 + f;
        outp[e] = __float2bfloat16((c[i] - mean) * rstd * g1[e] + b1[e]);
    }
}

// ---------------- fallback VALU GEMM ----------------
#define BM 64
#define BN 64
#define BKK 16
template<typename TA>
__global__ void gemm_kernel(const TA* __restrict__ A, const float* __restrict__ Bw,
                            const float* __restrict__ bias, const float* __restrict__ residual,
                            float* __restrict__ outF, bf16* __restrict__ outB,
                            int M, int N, int K, int act)
{
    __shared__ float As[BKK][BM + 4];
    __shared__ float Bs[BKK][BN + 4];
    int n0 = blockIdx.x * BN, m0 = blockIdx.y * BM;
    int tid = threadIdx.x;
    int tx = tid & 15, ty = tid >> 4;
    float acc[4][4] = {};
    for (int k0 = 0; k0 < K; k0 += BKK) {
        for (int i = tid; i < BM * BKK; i += 256) {
            int m = i >> 4, k = i & 15;
            As[k][m] = ldA(A, (size_t)(m0 + m) * K + k0 + k);
        }
        for (int i = tid; i < BKK * BN; i += 256) {
            int k = i >> 6, n = i & 63;
            int gn = n0 + n;
            Bs[k][n] = (gn < N) ? Bw[(size_t)(k0 + k) * N + gn] : 0.f;
        }
        __syncthreads();
        #pragma unroll
        for (int k = 0; k < BKK; ++k) {
            float a[4], bb[4];
            #pragma unroll
            for (int i = 0; i < 4; ++i) a[i] = As[k][ty * 4 + i];
            #pragma unroll
            for (int j = 0; j < 4; ++j) bb[j] = Bs[k][tx * 4 + j];
            #pragma unroll
            for (int i = 0; i < 4; ++i)
                #pragma unroll
                for (int j = 0; j < 4; ++j) acc[i][j] += a[i] * bb[j];
        }
        __syncthreads();
    }
    #pragma unroll
    for (int i = 0; i < 4; ++i) {
        int m = m0 + ty * 4 + i;
        #pragma unroll
        for (int j = 0; j < 4; ++j) {
            int n = n0 + tx * 4 + j;
            if (n >= N) continue;
            float v = acc[i][j];
            v += bias[n];
            if (act == 1)      v = 0.5f * v * (1.f + erff(v * 0.7071067811865476f));
            else if (act == 2) v = (v > 20.f) ? v : log1pf(__expf(v));
            if (residual) v += residual[(size_t)m * N + n];
            if (outB) stO(outB, (size_t)m * N + n, v);
            else      stO(outF, (size_t)m * N + n, v);
        }
    }
}

// ---------------- LayerNorm over dim 512 ----------------
__global__ void ln_kernel(const float* __restrict__ in, const float* __restrict__ g,
                          const float* __restrict__ bta, float* __restrict__ out, float eps)
{
    int row = blockIdx.x, tid = threadIdx.x;
    const float* r = in + (size_t)row * DM;
    float v0 = r[tid], v1 = r[tid + 256];
    float s1 = v0 + v1, s2 = v0 * v0 + v1 * v1;
    blk_red_sum2(s1, s2);
    float mean = s1 * (1.f / 512.f);
    float var  = s2 * (1.f / 512.f) - mean * mean;
    float rstd = rsqrtf(fmaxf(var, 0.f) + eps);
    float* o = out + (size_t)row * DM;
    o[tid]       = (v0 - mean) * rstd * g[tid]       + bta[tid];
    o[tid + 256] = (v1 - mean) * rstd * g[tid + 256] + bta[tid + 256];
}

// ---------------- qkv permute: [row][1536] fp32 -> q/k/v [b*8+h][s][64] bf16 ----------------
__global__ void permute_qkv(const float* __restrict__ qkvb, bf16* __restrict__ qh,
                            bf16* __restrict__ kh, bf16* __restrict__ vh)
{
    int r = blockIdx.x;          // b*256+s
    int b = r >> 8, s = r & 255;
    for (int c = threadIdx.x; c < 1536; c += 256) {
        int type = c >> 9;
        int inner = c & 511;
        int h = inner >> 6, d = inner & 63;
        bf16 v = __float2bfloat16(qkvb[(size_t)r * 1536 + c]);
        bf16* dst = (type == 0) ? qh : (type == 1 ? kh : vh);
        dst[((size_t)(b * 8 + h) * 256 + s) * 64 + d] = v;
    }
}

// ---------------- attention v3: registers-only softmax, head-major bf16 QKV ----------------
// grid: (b,h,qc) = 8*8*8 = 512 blocks; 256 threads; 32 q-rows per block.
__global__ __launch_bounds__(256, 4) void attn_kernel3(const bf16* __restrict__ qh,
        const bf16* __restrict__ kh, const bf16* __restrict__ vh,
        const float* __restrict__ rel_table, float* __restrict__ attno)
{
    __shared__ __align__(16) float Qs[32][68];
    __shared__ __align__(16) float KVs[64][68];
    __shared__ bf16 Ps[32][264];
    int blk = blockIdx.x;
    int qc = blk & 7; int bh = blk >> 3; int h = bh & 7; int b = bh >> 3;
    int q0 = qc * 32;
    int tid = threadIdx.x;
    const bf16* qb = qh + (size_t)bh * 256 * 64;
    const bf16* kb = kh + (size_t)bh * 256 * 64;
    const bf16* vb = vh + (size_t)bh * 256 * 64;

    // stage Q tile: 32 rows x 8 groups of 8
    {
        int row = tid >> 3, grp = tid & 7;
        short8 v = *(const short8*)((const short*)qb + (size_t)(q0 + row) * 64 + grp * 8);
        float4 f0 = {bs2f(v[0]), bs2f(v[1]), bs2f(v[2]), bs2f(v[3])};
        float4 f1 = {bs2f(v[4]), bs2f(v[5]), bs2f(v[6]), bs2f(v[7])};
        *(float4*)&Qs[row][grp * 8]     = f0;
        *(float4*)&Qs[row][grp * 8 + 4] = f1;
    }

    int tq = tid >> 3, kl = tid & 7;
    int gq = q0 + tq;
    float sc[4][8];
    float mx = -3e38f;

    // phase 1: scores (kept in registers)
    #pragma unroll
    for (int kc = 0; kc < 4; ++kc) {
        __syncthreads();
        #pragma unroll
        for (int idx = 0; idx < 2; ++idx) {
            int ii = tid + idx * 256;
            int row = ii >> 3, grp = ii & 7;
            short8 v = *(const short8*)((const short*)kb + (size_t)(kc * 64 + row) * 64 + grp * 8);
            float4 f0 = {bs2f(v[0]), bs2f(v[1]), bs2f(v[2]), bs2f(v[3])};
            float4 f1 = {bs2f(v[4]), bs2f(v[5]), bs2f(v[6]), bs2f(v[7])};
            *(float4*)&KVs[row][grp * 8]     = f0;
            *(float4*)&KVs[row][grp * 8 + 4] = f1;
        }
        __syncthreads();
        float s8[8] = {0.f, 0.f, 0.f, 0.f, 0.f, 0.f, 0.f, 0.f};
        for (int d0 = 0; d0 < 64; d0 += 16) {
            float4 qv0 = *(const float4*)&Qs[tq][d0];
            float4 qv1 = *(const float4*)&Qs[tq][d0 + 4];
            float4 qv2 = *(const float4*)&Qs[tq][d0 + 8];
            float4 qv3 = *(const float4*)&Qs[tq][d0 + 12];
            #pragma unroll
            for (int j = 0; j < 8; ++j) {
                int kk = kl * 8 + j;
                float4 k0 = *(const float4*)&KVs[kk][d0];
                float4 k1 = *(const float4*)&KVs[kk][d0 + 4];
                float4 k2 = *(const float4*)&KVs[kk][d0 + 8];
                float4 k3 = *(const float4*)&KVs[kk][d0 + 12];
                s8[j] += qv0.x * k0.x + qv0.y * k0.y + qv0.z * k0.z + qv0.w * k0.w
                       + qv1.x * k1.x + qv1.y * k1.y + qv1.z * k1.z + qv1.w * k1.w
                       + qv2.x * k2.x + qv2.y * k2.y + qv2.z * k2.z + qv2.w * k2.w
                       + qv3.x * k3.x + qv3.y * k3.y + qv3.z * k3.z + qv3.w * k3.w;
            }
        }
        #pragma unroll
        for (int j = 0; j < 8; ++j) {
            int gk = kc * 64 + kl * 8 + j;
            float s = s8[j] * 0.125f;
            int rel = gk - gq; rel = rel < -128 ? -128 : (rel > 128 ? 128 : rel);
            s += rel_table[h * 257 + rel + 128];
            if (gk > gq) s -= 1e9f;
            sc[kc][j] = s;
            mx = fmaxf(mx, s);
        }
    }
    // row max over the 8-lane group
    mx = fmaxf(mx, __shfl_xor(mx, 1, 64));
    mx = fmaxf(mx, __shfl_xor(mx, 2, 64));
    mx = fmaxf(mx, __shfl_xor(mx, 4, 64));
    // exp + sum, write P (bf16) to LDS
    float lsum = 0.f;
    #pragma unroll
    for (int kc = 0; kc < 4; ++kc)
        #pragma unroll
        for (int j = 0; j < 8; ++j) {
            float e = __expf(sc[kc][j] - mx);
            lsum += e;
            Ps[tq][kc * 64 + kl * 8 + j] = __float2bfloat16(e);
        }
    lsum += __shfl_xor(lsum, 1, 64);
    lsum += __shfl_xor(lsum, 2, 64);
    lsum += __shfl_xor(lsum, 4, 64);
    float inv = 1.f / lsum;

    // phase 2: P @ V — thread owns dims kl*8..kl*8+7 of row tq
    float o[8] = {0.f, 0.f, 0.f, 0.f, 0.f, 0.f, 0.f, 0.f};
    #pragma unroll
    for (int kc = 0; kc < 4; ++kc) {
        __syncthreads();
        #pragma unroll
        for (int idx = 0; idx < 2; ++idx) {
            int ii = tid + idx * 256;
            int row = ii >> 3, grp = ii & 7;
            short8 v = *(const short8*)((const short*)vb + (size_t)(kc * 64 + row) * 64 + grp * 8);
            float4 f0 = {bs2f(v[0]), bs2f(v[1]), bs2f(v[2]), bs2f(v[3])};
            float4 f1 = {bs2f(v[4]), bs2f(v[5]), bs2f(v[6]), bs2f(v[7])};
            *(float4*)&KVs[row][grp * 8]     = f0;
            *(float4*)&KVs[row][grp * 8 + 4] = f1;
        }
        __syncthreads();
        for (int kk = 0; kk < 64; ++kk) {
            float p = b2f(Ps[tq][kc * 64 + kk]);
            float4 v0 = *(const float4*)&KVs[kk][kl * 8];
            float4 v1 = *(const float4*)&KVs[kk][kl * 8 + 4];
            o[0] += p * v0.x; o[1] += p * v0.y; o[2] += p * v0.z; o[3] += p * v0.w;
            o[4] += p * v1.x; o[5] += p * v1.y; o[6] += p * v1.z; o[7] += p * v1.w;
        }
    }
    float* op = attno + (size_t)(b * 256 + gq) * DM + h * 64 + kl * 8;
    #pragma unroll
    for (int dj = 0; dj < 8; ++dj) op[dj] = o[dj] * inv;
}

// ---------------- mamba depthwise conv (k=4 causal) + silu ----------------
__global__ void mamba_conv_kernel(const bf16* __restrict__ xz, const float* __restrict__ cW,
                                  const float* __restrict__ cb, bf16* __restrict__ xc)
{
    int row = blockIdx.x;
    int b = row >> 8, t = row & 255;
    int tid = threadIdx.x;
    #pragma unroll
    for (int j = 0; j < 4; ++j) {
        int dd = tid + j * 256;
        float acc = cb[dd];
        #pragma unroll
        for (int k = 0; k < 4; ++k) {
            int ts = t - 3 + k;
            if (ts >= 0) acc += b2f(xz[((size_t)(b * 256 + ts)) * 2048 + dd]) * cW[dd * 4 + k];
        }
        xc[(size_t)row * DI + dd] = __float2bfloat16(acc * (1.f / (1.f + __expf(-acc))));
    }
}

// ---------------- selective scan v2: LDS-chunked (64 timesteps/chunk) ----------------
// grid: BSZ*(DI/16)=512 blocks, 256 threads = 16 s x 16 d.
__global__ __launch_bounds__(256) void scan_kernel2(const float* __restrict__ delta,
        const bf16* __restrict__ xcv, const float* __restrict__ bc,
        const bf16* __restrict__ xz, const float* __restrict__ Alog,
        const float* __restrict__ Dp, float* __restrict__ y)
{
    __shared__ __align__(16) float Ds[64][20];
    __shared__ __align__(16) float Us[64][20];
    __shared__ __align__(16) float Zs[64][20];
    __shared__ __align__(16) float BCs[64][32];
    int blk = blockIdx.x;
    int b = blk >> 6, chunk = blk & 63;
    int d0 = chunk * 16;
    int tid = threadIdx.x;
    int s = tid & 15, dl = tid >> 4;
    int d = d0 + dl;
    float A  = -__expf(Alog[d * DST + s]);
    float Dv = Dp[d];
    float h = 0.f;
    int stt = tid >> 2, sg = tid & 3;     // staging: row 0..63, float4-group 0..3
    int bt0 = tid >> 3, bg0 = tid & 7;    // bc staging: row, group
    int bt1 = (tid + 256) >> 3, bg1 = (tid + 256) & 7;

    for (int c = 0; c < 4; ++c) {
        int t0 = c * 64;
        __syncthreads();
        {
            size_t row = (size_t)(b * 256 + t0 + stt);
            float4 dv = *(const float4*)&delta[row * DI + d0 + sg * 4];
            *(float4*)&Ds[stt][sg * 4] = dv;
            short4 uv = *(const short4*)((const short*)xcv + row * DI + d0 + sg * 4);
            float4 uf = {bs2f(uv.x), bs2f(uv.y), bs2f(uv.z), bs2f(uv.w)};
            *(float4*)&Us[stt][sg * 4] = uf;
            short4 zv = *(const short4*)((const short*)xz + row * 2048 + DI + d0 + sg * 4);
            float4 zf;
            zf.x = bs2f(zv.x); zf.y = bs2f(zv.y); zf.z = bs2f(zv.z); zf.w = bs2f(zv.w);
            zf.x = zf.x * (1.f / (1.f + __expf(-zf.x)));
            zf.y = zf.y * (1.f / (1.f + __expf(-zf.y)));
            zf.z = zf.z * (1.f / (1.f + __expf(-zf.z)));
            zf.w = zf.w * (1.f / (1.f + __expf(-zf.w)));
            *(float4*)&Zs[stt][sg * 4] = zf;
            size_t row0 = (size_t)(b * 256 + t0 + bt0);
            *(float4*)&BCs[bt0][bg0 * 4] = *(const float4*)&bc[row0 * 32 + bg0 * 4];
            size_t row1 = (size_t)(b * 256 + t0 + bt1);
            *(float4*)&BCs[bt1][bg1 * 4] = *(const float4*)&bc[row1 * 32 + bg1 * 4];
        }
        __syncthreads();
        #pragma unroll 8
        for (int t = 0; t < 64; ++t) {
            float dt = Ds[t][dl];
            float u  = Us[t][dl];
            float Bv = BCs[t][s];
            float Cv = BCs[t][16 + s];
            h = __expf(dt * A) * h + dt * Bv * u;
            float contrib = h * Cv;
            contrib += __shfl_xor(contrib, 1, 64);
            contrib += __shfl_xor(contrib, 2, 64);
            contrib += __shfl_xor(contrib, 4, 64);
            contrib += __shfl_xor(contrib, 8, 64);
            if (s == 0)
                y[(size_t)(b * 256 + t0 + t) * DI + d] = (contrib + u * Dv) * Zs[t][dl];
        }
    }
}

// ---------------- old attention (fallback path) ----------------
__global__ void attn_kernel(const float* __restrict__ qkv, const float* __restrict__ rel_table,
                            float* __restrict__ attno)
{
    __shared__ float qv[64];
    __shared__ float sc[256];
    __shared__ float rb[256];
    __shared__ float op[4][64];
    int blk = blockIdx.x;
    int q = blk & 255, bh = blk >> 8;
    int hh = bh & 7, b = bh >> 3;
    int tid = threadIdx.x;
    const float* base = qkv + (size_t)b * 256 * 1536;
    if (tid < 64) qv[tid] = base[(size_t)q * 1536 + hh * 64 + tid];
    __syncthreads();
    const float* krow = base + (size_t)tid * 1536 + 512 + hh * 64;
    float d = 0.f;
    #pragma unroll 16
    for (int i = 0; i < 64; ++i) d += qv[i] * krow[i];
    float s = d * 0.125f;
    int rel = tid - q; rel = rel < -128 ? -128 : (rel > 128 ? 128 : rel);
    s += rel_table[hh * 257 + rel + 128];
    if (tid > q) s += -1e9f;
    sc[tid] = s; rb[tid] = s;
    __syncthreads();
    for (int st = 128; st > 0; st >>= 1) { if (tid < st) rb[tid] = fmaxf(rb[tid], rb[tid + st]); __syncthreads(); }
    float mx = rb[0];
    __syncthreads();
    float e = __expf(s - mx);
    sc[tid] = e; rb[tid] = e;
    __syncthreads();
    for (int st = 128; st > 0; st >>= 1) { if (tid < st) rb[tid] += rb[tid + st]; __syncthreads(); }
    float inv = 1.f / rb[0];
    __syncthreads();
    int dd = tid & 63, c = tid >> 6;
    const float* vbase = base + 1024 + hh * 64 + dd;
    float o = 0.f;
    for (int k = c * 64; k < c * 64 + 64; ++k) o += sc[k] * vbase[(size_t)k * 1536];
    op[c][dd] = o;
    __syncthreads();
    if (tid < 64) {
        float r = (op[0][tid] + op[1][tid] + op[2][tid] + op[3][tid]) * inv;
        attno[((size_t)(b * 256 + q)) * DM + hh * 64 + tid] = r;
    }
}

// ---------------- host helpers ----------------
template<typename TA>
static inline void launch_gemm(hipStream_t st, const TA* A, const float* Bw, const float* bias,
                               const float* res, float* outF, bf16* outB, int M, int N, int K, int act)
{
    dim3 grid((N + BN - 1) / BN, M / BM);
    gemm_kernel<TA><<<grid, 256, 0, st>>>(A, Bw, bias, res, outF, outB, M, N, K, act);
}

template<typename TA, typename TO>
static inline void launch_mfma(hipStream_t st, const TA* A, const short* BT, const float* bias,
                               const float* res, TO* out, int M, int N, int K, int act)
{
    dim3 grid(N / 64, M / 64);
    mfma_gemm64<TA, TO><<<grid, 256, 0, st>>>(A, BT, bias, res, out, M, N, K, act);
}

static inline void launch_transpose(hipStream_t st, const float* in, short* out,
                                    int K, int N, int layers, size_t in_ls, size_t out_ls)
{
    dim3 grid(N / 32, K / 32, layers);
    transpose_cvt<<<grid, 256, 0, st>>>(in, out, K, N, in_ls, out_ls);
}

extern "C" void kernel_launch(void* const* d_in, const int* in_sizes, int n_in,
                              void* d_out, int out_size, void* d_ws, size_t ws_size,
                              hipStream_t stream)
{
    const float* x_in     = (const float*)d_in[0];
    const float* day_w    = (const float*)d_in[1];
    const float* day_b    = (const float*)d_in[2];
    const float* gauss    = (const float*)d_in[3];
    const float* pe_ln1_g = (const float*)d_in[4];
    const float* pe_ln1_b = (const float*)d_in[5];
    const float* pe_W     = (const float*)d_in[6];
    const float* pe_b     = (const float*)d_in[7];
    const float* pe_ln2_g = (const float*)d_in[8];
    const float* pe_ln2_b = (const float*)d_in[9];
    const float* rel_tab  = (const float*)d_in[10];
    const float* tf_ln_g  = (const float*)d_in[11];
    const float* tf_ln_b  = (const float*)d_in[12];
    const float* tf_qkv_W = (const float*)d_in[13];
    const float* tf_qkv_b = (const float*)d_in[14];
    const float* tf_out_W = (const float*)d_in[15];
    const float* tf_out_b = (const float*)d_in[16];
    const float* tf_ffln_g= (const float*)d_in[17];
    const float* tf_ffln_b= (const float*)d_in[18];
    const float* tf_fc1_W = (const float*)d_in[19];
    const float* tf_fc1_b = (const float*)d_in[20];
    const float* tf_fc2_W = (const float*)d_in[21];
    const float* tf_fc2_b = (const float*)d_in[22];
    const float* mb_norm_g= (const float*)d_in[23];
    const float* mb_norm_b= (const float*)d_in[24];
    const float* mb_in_W  = (const float*)d_in[25];
    const float* mb_in_b  = (const float*)d_in[26];
    const float* mb_conv_W= (const float*)d_in[27];
    const float* mb_conv_b= (const float*)d_in[28];
    const float* mb_xp_W  = (const float*)d_in[29];
    const float* mb_xp_b  = (const float*)d_in[30];
    const float* mb_dt_W  = (const float*)d_in[31];
    const float* mb_dt_b  = (const float*)d_in[32];
    const float* mb_Alog  = (const float*)d_in[33];
    const float* mb_D     = (const float*)d_in[34];
    const float* mb_out_W = (const float*)d_in[35];
    const float* mb_out_b = (const float*)d_in[36];
    const float* head_W   = (const float*)d_in[37];
    const float* head_b   = (const float*)d_in[38];
    const int*   day_idx  = (const int*)d_in[39];

    bool big = ws_size >= ((size_t)59 << 20);

    if (big) {
        char* base = (char*)d_ws;
        short* wT = (short*)base;
        float* x_state = (float*)(base + ((size_t)22 << 20));
        char* arena = base + ((size_t)26 << 20);

        bf16*  pe_v  = (bf16*)arena;                           // 32 MB
        float* hbuf  = (float*)arena;                          // 4 MB
        float* qkvb  = (float*)(arena + ((size_t)4  << 20));   // 12 MB
        float* attno = (float*)(arena + ((size_t)16 << 20));   // 4 MB
        bf16*  ffb   = (bf16*) (arena + ((size_t)20 << 20));   // 8 MB (lifetime disjoint w/ qh/kh/vh)
        bf16*  qh    = (bf16*) (arena + ((size_t)20 << 20));   // 2 MB
        bf16*  kh    = (bf16*) (arena + ((size_t)22 << 20));   // 2 MB
        bf16*  vh    = (bf16*) (arena + ((size_t)24 << 20));   // 2 MB
        bf16*  xzb   = (bf16*) (arena + ((size_t)4  << 20));   // 8 MB
        bf16*  xcb   = (bf16*) (arena + ((size_t)12 << 20));   // 4 MB
        float* deltab= (float*)(arena + ((size_t)16 << 20));   // 8 MB
        float* yb    = (float*)(arena + ((size_t)24 << 20));   // 8 MB
        float* bcb   = (float*)(arena + ((size_t)32 << 20));   // 0.25 MB

        const size_t qkvT_o = 0,            qkvT_ls = (size_t)1536 * 512;
        const size_t outT_o = 1572864,      outT_ls = (size_t)512 * 512;
        const size_t fc1T_o = 2097152,      fc1T_ls = (size_t)2048 * 512;
        const size_t fc2T_o = 4194304,      fc2T_ls = (size_t)512 * 2048;
        const size_t inT_o  = 0,            inT_ls  = (size_t)2048 * 512;
        const size_t dtT_o  = 4194304,      dtT_ls  = (size_t)1024 * 1024;
        const size_t owT_o  = 8388608,      owT_ls  = (size_t)512 * 1024;

        // ---- stage A ----
        launch_transpose(stream, pe_W, wT, 8192, 512, 1, 0, 0);
        patch_kernel<<<MROWS, 256, 0, stream>>>(x_in, day_w, day_b, gauss, pe_ln1_g, pe_ln1_b,
                                                day_idx, pe_v);
        launch_mfma(stream, (const short*)pe_v, wT, pe_b, (const float*)nullptr, x_state,
                    MROWS, DM, KL * NFEAT, 0);
        ln_kernel<<<MROWS, 256, 0, stream>>>(x_state, pe_ln2_g, pe_ln2_b, x_state, 1e-6f);

        // ---- transformer weights ----
        launch_transpose(stream, tf_qkv_W, wT + qkvT_o, 512, 1536, 2, (size_t)512 * 1536, qkvT_ls);
        launch_transpose(stream, tf_out_W, wT + outT_o, 512, 512, 2, (size_t)512 * 512, outT_ls);
        launch_transpose(stream, tf_fc1_W, wT + fc1T_o, 512, 2048, 2, (size_t)512 * 2048, fc1T_ls);
        launch_transpose(stream, tf_fc2_W, wT + fc2T_o, 2048, 512, 2, (size_t)2048 * 512, fc2T_ls);

        for (int i = 0; i < 2; ++i) {
            ln_kernel<<<MROWS, 256, 0, stream>>>(x_state, tf_ln_g + i * DM, tf_ln_b + i * DM, hbuf, 1e-5f);
            launch_mfma(stream, hbuf, wT + qkvT_o + i * qkvT_ls, tf_qkv_b + i * 3 * DM,
                        (const float*)nullptr, qkvb, MROWS, 3 * DM, DM, 0);
            permute_qkv<<<MROWS, 256, 0, stream>>>(qkvb, qh, kh, vh);
            attn_kernel3<<<BSZ * NHEAD_ * 8, 256, 0, stream>>>(qh, kh, vh, rel_tab, attno);
            launch_mfma(stream, attno, wT + outT_o + i * outT_ls, tf_out_b + i * DM,
                        x_state, x_state, MROWS, DM, DM, 0);
            ln_kernel<<<MROWS, 256, 0, stream>>>(x_state, tf_ffln_g + i * DM, tf_ffln_b + i * DM, hbuf, 1e-5f);
            launch_mfma(stream, hbuf, wT + fc1T_o + i * fc1T_ls, tf_fc1_b + i * FFD,
                        (const float*)nullptr, ffb, MROWS, FFD, DM, 1);
            launch_mfma(stream, (const short*)ffb, wT + fc2T_o + i * fc2T_ls, tf_fc2_b + i * DM,
                        x_state, x_state, MROWS, DM, FFD, 0);
        }

        // ---- mamba weights ----
        launch_transpose(stream, mb_in_W, wT + inT_o, 512, 2048, 4, (size_t)512 * 2048, inT_ls);
        launch_transpose(stream, mb_dt_W, wT + dtT_o, 1024, 1024, 4, (size_t)1024 * 1024, dtT_ls);
        launch_transpose(stream, mb_out_W, wT + owT_o, 1024, 512, 4, (size_t)1024 * 512, owT_ls);

        for (int i = 0; i < 4; ++i) {
            ln_kernel<<<MROWS, 256, 0, stream>>>(x_state, mb_norm_g + i * DM, mb_norm_b + i * DM, hbuf, 1e-5f);
            launch_mfma(stream, hbuf, wT + inT_o + i * inT_ls, mb_in_b + i * 2 * DI,
                        (const float*)nullptr, xzb, MROWS, 2 * DI, DM, 0);
            mamba_conv_kernel<<<MROWS, 256, 0, stream>>>(xzb, mb_conv_W + (size_t)i * DI * 4,
                                                         mb_conv_b + i * DI, xcb);
            skinny_gemm<<<MROWS / 8, 256, 0, stream>>>((const short*)xcb,
                        mb_xp_W + (size_t)i * DI * 2 * DST, mb_xp_b + i * 2 * DST,
                        bcb, MROWS, 2 * DST, DI);
            launch_mfma(stream, (const short*)xcb, wT + dtT_o + i * dtT_ls, mb_dt_b + i * DI,
                        (const float*)nullptr, deltab, MROWS, DI, DI, 2);
            scan_kernel2<<<BSZ * (DI / 16), 256, 0, stream>>>(deltab, xcb, bcb, xzb,
                                                              mb_Alog + (size_t)i * DI * DST,
                                                              mb_D + i * DI, yb);
            launch_mfma(stream, yb, wT + owT_o + i * owT_ls, mb_out_b + i * DM,
                        x_state, x_state, MROWS, DM, DI, 0);
        }

        skinny_gemm<<<MROWS / 8, 256, 0, stream>>>(x_state, head_W, head_b,
                    (float*)d_out, MROWS, NPHD, DM);
    } else {
        // ---- fallback: all-VALU path ----
        char* base = (char*)d_ws;
        float* x_state = (float*)base;
        char* arena = base + ((size_t)4 << 20);
        bf16* pe_v = (bf16*)arena;
        float* hbuf  = (float*)arena;
        float* qkvb  = (float*)(arena + ((size_t)4  << 20));
        float* attno = (float*)(arena + ((size_t)16 << 20));
        bf16*  ffb   = (bf16*) (arena + ((size_t)20 << 20));
        bf16*  xzb   = (bf16*) (arena + ((size_t)4  << 20));
        bf16*  xcb   = (bf16*) (arena + ((size_t)12 << 20));
        float* deltab= (float*)(arena + ((size_t)16 << 20));
        float* yb    = (float*)(arena + ((size_t)24 << 20));
        float* bcb   = (float*)(arena + ((size_t)32 << 20));

        patch_kernel<<<MROWS, 256, 0, stream>>>(x_in, day_w, day_b, gauss, pe_ln1_g, pe_ln1_b,
                                                day_idx, pe_v);
        launch_gemm(stream, pe_v, pe_W, pe_b, (const float*)nullptr, x_state, (bf16*)nullptr,
                    MROWS, DM, KL * NFEAT, 0);
        ln_kernel<<<MROWS, 256, 0, stream>>>(x_state, pe_ln2_g, pe_ln2_b, x_state, 1e-6f);
        for (int i = 0; i < 2; ++i) {
            ln_kernel<<<MROWS, 256, 0, stream>>>(x_state, tf_ln_g + i * DM, tf_ln_b + i * DM, hbuf, 1e-5f);
            launch_gemm(stream, hbuf, tf_qkv_W + (size_t)i * DM * 3 * DM, tf_qkv_b + i * 3 * DM,
                        (const float*)nullptr, qkvb, (bf16*)nullptr, MROWS, 3 * DM, DM, 0);
            attn_kernel<<<BSZ * NHEAD_ * SP, 256, 0, stream>>>(qkvb, rel_tab, attno);
            launch_gemm(stream, attno, tf_out_W + (size_t)i * DM * DM, tf_out_b + i * DM,
                        x_state, x_state, (bf16*)nullptr, MROWS, DM, DM, 0);
            ln_kernel<<<MROWS, 256, 0, stream>>>(x_state, tf_ffln_g + i * DM, tf_ffln_b + i * DM, hbuf, 1e-5f);
            launch_gemm(stream, hbuf, tf_fc1_W + (size_t)i * DM * FFD, tf_fc1_b + i * FFD,
                        (const float*)nullptr, (float*)nullptr, ffb, MROWS, FFD, DM, 1);
            launch_gemm(stream, ffb, tf_fc2_W + (size_t)i * FFD * DM, tf_fc2_b + i * DM,
                        x_state, x_state, (bf16*)nullptr, MROWS, DM, FFD, 0);
        }
        for (int i = 0; i < 4; ++i) {
            ln_kernel<<<MROWS, 256, 0, stream>>>(x_state, mb_norm_g + i * DM, mb_norm_b + i * DM, hbuf, 1e-5f);
            launch_gemm(stream, hbuf, mb_in_W + (size_t)i * DM * 2 * DI, mb_in_b + i * 2 * DI,
                        (const float*)nullptr, (float*)nullptr, xzb, MROWS, 2 * DI, DM, 0);
            mamba_conv_kernel<<<MROWS, 256, 0, stream>>>(xzb, mb_conv_W + (size_t)i * DI * 4,
                                                         mb_conv_b + i * DI, xcb);
            launch_gemm(stream, xcb, mb_xp_W + (size_t)i * DI * 2 * DST, mb_xp_b + i * 2 * DST,
                        (const float*)nullptr, bcb, (bf16*)nullptr, MROWS, 2 * DST, DI, 0);
            launch_gemm(stream, xcb, mb_dt_W + (size_t)i * DI * DI, mb_dt_b + i * DI,
                        (const float*)nullptr, deltab, (bf16*)nullptr, MROWS, DI, DI, 2);
            scan_kernel2<<<BSZ * (DI / 16), 256, 0, stream>>>(deltab, xcb, bcb, xzb,
                                                              mb_Alog + (size_t)i * DI * DST,
                                                              mb_D + i * DI, yb);
            launch_gemm(stream, yb, mb_out_W + (size_t)i * DI * DM, mb_out_b + i * DM,
                        x_state, x_state, (bf16*)nullptr, MROWS, DM, DI, 0);
        }
        launch_gemm(stream, x_state, head_W, head_b, (const float*)nullptr, (float*)d_out, (bf16*)nullptr,
                    MROWS, NPHD, DM, 0);
    }
}